// Round 5
// baseline (4873.861 us; speedup 1.0000x reference)
//
#include <hip/hip_runtime.h>
#include <hip/hip_bf16.h>
#include <math.h>

typedef __bf16 bf16;

#define N_ENT   100000
#define N_REL   16
#define N_EDGES 1600000
#define OUT_STRIDE 160
#define NCHUNK  98   // ceil(N_ENT/1024)

// ---------- zero an int region (grid-stride) ----------
__global__ __launch_bounds__(256) void zero_kernel(int* __restrict__ p, int n) {
    int i = blockIdx.x * 256 + threadIdx.x;
    int stride = gridDim.x * 256;
    for (; i < n; i += stride) p[i] = 0;
}

// ---------- ws-too-small tripwire: all-zero output (absmax ~0.9375 signature) ----------
__global__ __launch_bounds__(256) void zero_out_kernel(float* __restrict__ out, int n) {
    int i = blockIdx.x * 256 + threadIdx.x;
    int stride = gridDim.x * 256;
    for (; i < n; i += stride) out[i] = 0.f;
}

// ---------- projection for relation r: projR[n][j] = (bf16) sum_d ent[n][d] * Wr[d][j] ----------
// VALU shuffle-broadcast. 16 nodes per block. fp32 inputs, fp32 accumulate, bf16 store.
__global__ __launch_bounds__(256) void projr_simple(const float* __restrict__ ent,
                                                    const float* __restrict__ Wr,
                                                    bf16* __restrict__ projR) {
    __shared__ float Ws[64 * 65];
    int t = threadIdx.x;
    for (int idx = t; idx < 4096; idx += 256) { int d = idx >> 6, j = idx & 63; Ws[d * 65 + j] = Wr[idx]; }
    __syncthreads();
    int wave = t >> 6, j = t & 63;
#pragma unroll
    for (int nn = 0; nn < 4; ++nn) {
        int node = blockIdx.x * 16 + nn * 4 + wave;
        if (node >= N_ENT) continue;
        float x = ent[(size_t)node * 64 + j];
        float acc = 0.f;
#pragma unroll
        for (int d = 0; d < 64; ++d) acc += __shfl(x, d) * Ws[d * 65 + j];
        projR[(size_t)node * 64 + j] = (bf16)acc;
    }
}

// ---------- dst-degree histogram ----------
__global__ __launch_bounds__(256) void hist_kernel(const int* __restrict__ dst, int* __restrict__ cnt) {
    int e = blockIdx.x * 256 + threadIdx.x;
    if (e < N_EDGES) atomicAdd(&cnt[dst[e]], 1);
}

// ---------- dst-CSR scans ----------
__global__ __launch_bounds__(256) void scan1(const int* __restrict__ cnt, int* __restrict__ part) {
    __shared__ int sh[256];
    int bIdx = blockIdx.x, t = threadIdx.x;
    int i0 = bIdx * 1024 + t * 4;
    int s = 0;
#pragma unroll
    for (int u = 0; u < 4; ++u) { int i = i0 + u; if (i < N_ENT) s += cnt[i]; }
    sh[t] = s; __syncthreads();
    for (int o = 128; o > 0; o >>= 1) { if (t < o) sh[t] += sh[t + o]; __syncthreads(); }
    if (t == 0) part[bIdx] = sh[0];
}

__global__ void scan2(const int* __restrict__ part, int* __restrict__ pbase) {
    if (threadIdx.x == 0) {
        int s = 0;
        for (int i = 0; i < NCHUNK; ++i) { pbase[i] = s; s += part[i]; }
    }
}

__global__ __launch_bounds__(256) void scan3(const int* __restrict__ cnt, const int* __restrict__ pbase,
                                             int* __restrict__ row_ptr, int* __restrict__ cursor) {
    __shared__ int sh[256];
    int bIdx = blockIdx.x, t = threadIdx.x;
    int i0 = bIdx * 1024 + t * 4;
    int c[4]; int s = 0;
#pragma unroll
    for (int u = 0; u < 4; ++u) { c[u] = (i0 + u < N_ENT) ? cnt[i0 + u] : 0; s += c[u]; }
    sh[t] = s; __syncthreads();
    for (int o = 1; o < 256; o <<= 1) {
        int add = (t >= o) ? sh[t - o] : 0;
        __syncthreads();
        sh[t] += add;
        __syncthreads();
    }
    int run = pbase[bIdx] + sh[t] - s;
#pragma unroll
    for (int u = 0; u < 4; ++u) {
        if (i0 + u < N_ENT) { row_ptr[i0 + u] = run; cursor[i0 + u] = run; run += c[u]; }
    }
    if (bIdx == 0 && t == 0) row_ptr[N_ENT] = N_EDGES;
}

// maps dst-CSR slot p -> original edge index e
__global__ __launch_bounds__(256) void dst_scatter(const int* __restrict__ dst, int* __restrict__ cursor,
                                                   int* __restrict__ eid) {
    int e = blockIdx.x * 256 + threadIdx.x;
    if (e >= N_EDGES) return;
    int d = dst[e];
    int p = atomicAdd(&cursor[d], 1);
    eid[p] = e;
}

// ---------- attention for relation r over ALL edges (skip non-matching) ----------
__global__ __launch_bounds__(256) void attr_simple(const bf16* __restrict__ projR, const float* __restrict__ rel,
                                                   const int* __restrict__ src, const int* __restrict__ dst,
                                                   const int* __restrict__ ety, int r, float* __restrict__ att) {
    int lane = threadIdx.x & 63;
    int wid = blockIdx.x * 4 + (threadIdx.x >> 6);
    int nw = gridDim.x * 4;
    float rl = rel[r * 64 + lane];
    for (int i = wid; i < N_EDGES; i += nw) {
        if (ety[i] != r) continue;           // wave-uniform scalar read
        int s = src[i], d = dst[i];
        float tt = (float)projR[(size_t)s * 64 + lane];
        float hh = (float)projR[(size_t)d * 64 + lane];
        float z = hh + rl;
        float ez = __expf(2.f * z);          // tanh(z) = 1 - 2/(e^{2z}+1), saturates safely
        float v = tt * (1.f - 2.f / (ez + 1.f));
#pragma unroll
        for (int o = 1; o < 64; o <<= 1) v += __shfl_xor(v, o);
        if (lane == 0) att[i] = v;
    }
}

// ---------- per-dst softmax (att gathered via eid, w written dense in dst-CSR order) ----------
__global__ __launch_bounds__(256) void softmax_kernel(const int* __restrict__ row_ptr, const int* __restrict__ eid,
                                                      const float* __restrict__ att, float* __restrict__ w) {
    int node = blockIdx.x * 4 + (threadIdx.x >> 6);
    if (node >= N_ENT) return;
    int lane = threadIdx.x & 63;
    int r0 = row_ptr[node], r1 = row_ptr[node + 1];
    if (r0 >= r1) return;
    float m = -__builtin_inff();
    for (int k = r0 + lane; k < r1; k += 64) m = fmaxf(m, att[eid[k]]);
#pragma unroll
    for (int o = 1; o < 64; o <<= 1) m = fmaxf(m, __shfl_xor(m, o));
    float s = 0.f;
    for (int k = r0 + lane; k < r1; k += 64) s += __expf(att[eid[k]] - m);
#pragma unroll
    for (int o = 1; o < 64; o <<= 1) s += __shfl_xor(s, o);
    float inv = (s > 0.f) ? 1.f / s : 0.f;
    for (int k = r0 + lane; k < r1; k += 64) w[k] = __expf(att[eid[k]] - m) * inv;
}

// ---------- aggregation (fp32 feat): aggb[n][j] = (bf16) sum_k w[k] * feat[src[eid[k]]][j] ----------
__global__ __launch_bounds__(256) void agg_f32(const int* __restrict__ row_ptr, const int* __restrict__ eid,
                                               const int* __restrict__ src, const float* __restrict__ w,
                                               const float* __restrict__ feat, bf16* __restrict__ aggb) {
    int node = blockIdx.x * 4 + (threadIdx.x >> 6);
    if (node >= N_ENT) return;
    int lane = threadIdx.x & 63;
    int r0 = row_ptr[node], r1 = row_ptr[node + 1];
    float acc = 0.f;
    for (int k = r0; k < r1; ++k) {
        int s = src[eid[k]];
        acc += w[k] * feat[(size_t)s * 64 + lane];
    }
    aggb[(size_t)node * 64 + lane] = (bf16)acc;
}

// ---------- aggregation (bf16 feat) ----------
__global__ __launch_bounds__(256) void agg_b16(const int* __restrict__ row_ptr, const int* __restrict__ eid,
                                               const int* __restrict__ src, const float* __restrict__ w,
                                               const bf16* __restrict__ feat, bf16* __restrict__ aggb) {
    int node = blockIdx.x * 4 + (threadIdx.x >> 6);
    if (node >= N_ENT) return;
    int lane = threadIdx.x & 63;
    int r0 = row_ptr[node], r1 = row_ptr[node + 1];
    float acc = 0.f;
    for (int k = r0; k < r1; ++k) {
        int s = src[eid[k]];
        acc += w[k] * (float)feat[(size_t)s * 64 + lane];
    }
    aggb[(size_t)node * 64 + lane] = (bf16)acc;
}

// ---------- layer 1: h1 = lrelu((h0*agg) @ W0); out[:,0:64]=h0; out[:,64:128]=l2n(h1) ----------
__global__ __launch_bounds__(256) void transform1_kernel(const float* __restrict__ ent, const bf16* __restrict__ aggb,
                                                         const float* __restrict__ W0, bf16* __restrict__ h1b,
                                                         float* __restrict__ out) {
    __shared__ float Ws[64 * 65];
    int t = threadIdx.x;
    for (int idx = t; idx < 4096; idx += 256) { int d = idx >> 6, j = idx & 63; Ws[d * 65 + j] = W0[idx]; }
    __syncthreads();
    int node = blockIdx.x * 4 + (t >> 6);
    if (node >= N_ENT) return;
    int j = t & 63;
    float h0v = ent[(size_t)node * 64 + j];
    float x = h0v * (float)aggb[(size_t)node * 64 + j];
    float acc = 0.f;
#pragma unroll
    for (int d = 0; d < 64; ++d) acc += __shfl(x, d) * Ws[d * 65 + j];
    float h1v = acc > 0.f ? acc : 0.01f * acc;
    h1b[(size_t)node * 64 + j] = (bf16)h1v;
    float ss = h1v * h1v;
#pragma unroll
    for (int o = 1; o < 64; o <<= 1) ss += __shfl_xor(ss, o);
    float inv = 1.f / fmaxf(sqrtf(ss), 1e-12f);
    out[(size_t)node * OUT_STRIDE + j] = h0v;
    out[(size_t)node * OUT_STRIDE + 64 + j] = h1v * inv;
}

// ---------- layer 2: h2 = lrelu((h1*agg2) @ W1); out[:,128:160]=l2n(h2) ----------
__global__ __launch_bounds__(256) void transform2_kernel(const bf16* __restrict__ h1b, const bf16* __restrict__ aggb,
                                                         const float* __restrict__ W1, float* __restrict__ out) {
    __shared__ float Ws[64 * 33];
    int t = threadIdx.x;
    for (int idx = t; idx < 2048; idx += 256) { int d = idx >> 5, j = idx & 31; Ws[d * 33 + j] = W1[idx]; }
    __syncthreads();
    int node = blockIdx.x * 4 + (t >> 6);
    if (node >= N_ENT) return;
    int j = t & 63;
    float x = (float)h1b[(size_t)node * 64 + j] * (float)aggb[(size_t)node * 64 + j];
    int base = j & 32, jj = j & 31;   // lanes 0..31 sum d=0..31; lanes 32..63 sum d=32..63
    float acc = 0.f;
#pragma unroll
    for (int i = 0; i < 32; ++i) acc += __shfl(x, base + i) * Ws[(base + i) * 33 + jj];
    acc += __shfl_xor(acc, 32);       // both halves now hold full h2_jj
    float h2 = acc > 0.f ? acc : 0.01f * acc;
    float ss = h2 * h2;
#pragma unroll
    for (int o = 1; o < 32; o <<= 1) ss += __shfl_xor(ss, o);   // per-half reduction = full norm (no double count)
    float inv = 1.f / fmaxf(sqrtf(ss), 1e-12f);
    if (j < 32) out[(size_t)node * OUT_STRIDE + 128 + jj] = h2 * inv;
}

extern "C" void kernel_launch(void* const* d_in, const int* in_sizes, int n_in,
                              void* d_out, int out_size, void* d_ws, size_t ws_size,
                              hipStream_t stream) {
    const float* ent = (const float*)d_in[0];
    const float* rel = (const float*)d_in[1];
    const float* W_R = (const float*)d_in[2];
    const float* W0  = (const float*)d_in[3];
    const float* W1  = (const float*)d_in[4];
    const int*   src = (const int*)d_in[5];
    const int*   dst = (const int*)d_in[6];
    const int*   ety = (const int*)d_in[7];
    float* out = (float*)d_out;

    char* ws = (char*)d_ws;
    size_t off = 0;
    auto take = [&](size_t bytes) -> char* {
        char* p = ws + off;
        off += (bytes + 255) & ~(size_t)255;
        return p;
    };
    int*   eid   = (int*)take((size_t)N_EDGES * 4);       // 6.4 MB
    float* w     = (float*)take((size_t)N_EDGES * 4);     // 6.4 MB  -- w, att, cnt contiguous (zeroed together)
    float* att   = (float*)take((size_t)N_EDGES * 4);     // 6.4 MB
    int*   cnt   = (int*)take((size_t)N_ENT * 4);         // 0.4 MB
    int*   rowp  = (int*)take((size_t)(N_ENT + 1) * 4);
    int*   cur   = (int*)take((size_t)N_ENT * 4);
    int*   part  = (int*)take(NCHUNK * 4);
    int*   pbase = (int*)take(NCHUNK * 4);
    bf16*  projR = (bf16*)take((size_t)N_ENT * 64 * 2);   // 12.8 MB (dead after attr loop)
    bf16*  h1b   = (bf16*)take((size_t)N_ENT * 64 * 2);   // 12.8 MB
    bf16*  aggb  = projR;   // sole overlay: projR last read in attr loop, aggb first written after
    size_t needed = off;    // ~46 MB

    if (needed > ws_size) {
        zero_out_kernel<<<512, 256, 0, stream>>>(out, out_size);
        return;
    }

    // zero {w, att, cnt}: contiguous ints (region sizes are 256B multiples -> no gaps)
    zero_kernel<<<2048, 256, 0, stream>>>((int*)w, 2 * N_EDGES + N_ENT);

    hist_kernel<<<N_EDGES / 256, 256, 0, stream>>>(dst, cnt);
    scan1<<<NCHUNK, 256, 0, stream>>>(cnt, part);
    scan2<<<1, 64, 0, stream>>>(part, pbase);
    scan3<<<NCHUNK, 256, 0, stream>>>(cnt, pbase, rowp, cur);
    dst_scatter<<<N_EDGES / 256, 256, 0, stream>>>(dst, cur, eid);

    for (int r = 0; r < N_REL; ++r) {
        projr_simple<<<(N_ENT + 15) / 16, 256, 0, stream>>>(ent, W_R + (size_t)r * 4096, projR);
        attr_simple<<<1024, 256, 0, stream>>>(projR, rel, src, dst, ety, r, att);
    }

    softmax_kernel<<<N_ENT / 4, 256, 0, stream>>>(rowp, eid, att, w);
    agg_f32<<<N_ENT / 4, 256, 0, stream>>>(rowp, eid, src, w, ent, aggb);
    transform1_kernel<<<N_ENT / 4, 256, 0, stream>>>(ent, aggb, W0, h1b, out);
    agg_b16<<<N_ENT / 4, 256, 0, stream>>>(rowp, eid, src, w, h1b, aggb);
    transform2_kernel<<<N_ENT / 4, 256, 0, stream>>>(h1b, aggb, W1, out);
}

// Round 7
// 2612.534 us; speedup vs baseline: 1.8656x; 1.8656x over previous
//
#include <hip/hip_runtime.h>
#include <hip/hip_bf16.h>
#include <math.h>

typedef __bf16 bf16;

#define N_ENT   100000
#define N_REL   16
#define N_EDGES 1600000
#define OUT_STRIDE 160
#define NCHUNK  98   // ceil(N_ENT/1024)

// ---------- zero an int region (grid-stride) ----------
__global__ __launch_bounds__(256) void zero_kernel(int* __restrict__ p, int n) {
    int i = blockIdx.x * 256 + threadIdx.x;
    int stride = gridDim.x * 256;
    for (; i < n; i += stride) p[i] = 0;
}

// ---------- ws-too-small tripwire: all-zero output (absmax ~0.9375 signature) ----------
__global__ __launch_bounds__(256) void zero_out_kernel(float* __restrict__ out, int n) {
    int i = blockIdx.x * 256 + threadIdx.x;
    int stride = gridDim.x * 256;
    for (; i < n; i += stride) out[i] = 0.f;
}

// ---------- projection for relation r: projR[n][j] = (bf16) sum_d ent[n][d] * Wr[d][j] ----------
__global__ __launch_bounds__(256) void projr_simple(const float* __restrict__ ent,
                                                    const float* __restrict__ Wr,
                                                    bf16* __restrict__ projR) {
    __shared__ float Ws[64 * 65];
    int t = threadIdx.x;
    for (int idx = t; idx < 4096; idx += 256) { int d = idx >> 6, j = idx & 63; Ws[d * 65 + j] = Wr[idx]; }
    __syncthreads();
    int wave = t >> 6, j = t & 63;
#pragma unroll
    for (int nn = 0; nn < 4; ++nn) {
        int node = blockIdx.x * 16 + nn * 4 + wave;
        if (node >= N_ENT) continue;
        float x = ent[(size_t)node * 64 + j];
        float acc = 0.f;
#pragma unroll
        for (int d = 0; d < 64; ++d) acc += __shfl(x, d) * Ws[d * 65 + j];
        projR[(size_t)node * 64 + j] = (bf16)acc;
    }
}

// ---------- fused histograms: dst-degree (global) + etype bins (LDS-staged) ----------
__global__ __launch_bounds__(256) void hist_kernel(const int* __restrict__ dst, const int* __restrict__ ety,
                                                   int* __restrict__ cnt, int* __restrict__ cnt16) {
    __shared__ int h16[16];
    int t = threadIdx.x;
    if (t < 16) h16[t] = 0;
    __syncthreads();
    int e = blockIdx.x * 256 + t;
    if (e < N_EDGES) {
        atomicAdd(&cnt[dst[e]], 1);
        atomicAdd(&h16[ety[e]], 1);
    }
    __syncthreads();
    if (t < 16 && h16[t] > 0) atomicAdd(&cnt16[t], h16[t]);
}

__global__ void bucket_scan(const int* __restrict__ cnt16, int* __restrict__ bptr, int* __restrict__ cur16) {
    if (threadIdx.x == 0) {
        int s = 0;
        for (int r = 0; r < N_REL; ++r) { bptr[r] = s; cur16[r] = s; s += cnt16[r]; }
        bptr[N_REL] = s;
    }
}

// ballot-rank scatter into 16 etype buckets (block-level reservation on 16 counters)
__global__ __launch_bounds__(256) void bucket_scatter(const int* __restrict__ src, const int* __restrict__ dst,
                                                      const int* __restrict__ ety, int* __restrict__ cur16,
                                                      int* __restrict__ bsrc, int* __restrict__ bdst) {
    __shared__ int whist[4][16];
    __shared__ int wbase[4][16];
    __shared__ int bbase[16];
    int t = threadIdx.x, wave = t >> 6, lane = t & 63;
    int e = blockIdx.x * 256 + t;
    int b = (e < N_EDGES) ? ety[e] : -1;
    unsigned long long ltmask = (1ull << lane) - 1ull;
    int rank = 0;
#pragma unroll
    for (int r = 0; r < 16; ++r) {
        unsigned long long mk = __ballot(b == r);
        if (b == r) rank = __popcll(mk & ltmask);
        if (lane == r) whist[wave][r] = __popcll(mk);
    }
    __syncthreads();
    if (t < 16) {
        int s0 = whist[0][t], s1 = whist[1][t], s2 = whist[2][t], s3 = whist[3][t];
        bbase[t] = atomicAdd(&cur16[t], s0 + s1 + s2 + s3);
        wbase[0][t] = 0; wbase[1][t] = s0; wbase[2][t] = s0 + s1; wbase[3][t] = s0 + s1 + s2;
    }
    __syncthreads();
    if (b >= 0) {
        int pos = bbase[b] + wbase[wave][b] + rank;
        bsrc[pos] = src[e];
        bdst[pos] = dst[e];
    }
}

// ---------- dst-CSR scans ----------
__global__ __launch_bounds__(256) void scan1(const int* __restrict__ cnt, int* __restrict__ part) {
    __shared__ int sh[256];
    int bIdx = blockIdx.x, t = threadIdx.x;
    int i0 = bIdx * 1024 + t * 4;
    int s = 0;
#pragma unroll
    for (int u = 0; u < 4; ++u) { int i = i0 + u; if (i < N_ENT) s += cnt[i]; }
    sh[t] = s; __syncthreads();
    for (int o = 128; o > 0; o >>= 1) { if (t < o) sh[t] += sh[t + o]; __syncthreads(); }
    if (t == 0) part[bIdx] = sh[0];
}

__global__ void scan2(const int* __restrict__ part, int* __restrict__ pbase) {
    if (threadIdx.x == 0) {
        int s = 0;
        for (int i = 0; i < NCHUNK; ++i) { pbase[i] = s; s += part[i]; }
    }
}

__global__ __launch_bounds__(256) void scan3(const int* __restrict__ cnt, const int* __restrict__ pbase,
                                             int* __restrict__ row_ptr, int* __restrict__ cursor) {
    __shared__ int sh[256];
    int bIdx = blockIdx.x, t = threadIdx.x;
    int i0 = bIdx * 1024 + t * 4;
    int c[4]; int s = 0;
#pragma unroll
    for (int u = 0; u < 4; ++u) { c[u] = (i0 + u < N_ENT) ? cnt[i0 + u] : 0; s += c[u]; }
    sh[t] = s; __syncthreads();
    for (int o = 1; o < 256; o <<= 1) {
        int add = (t >= o) ? sh[t - o] : 0;
        __syncthreads();
        sh[t] += add;
        __syncthreads();
    }
    int run = pbase[bIdx] + sh[t] - s;
#pragma unroll
    for (int u = 0; u < 4; ++u) {
        if (i0 + u < N_ENT) { row_ptr[i0 + u] = run; cursor[i0 + u] = run; run += c[u]; }
    }
    if (bIdx == 0 && t == 0) row_ptr[N_ENT] = N_EDGES;
}

// dst-CSR slot p <- {bucket index i (for att gather), permuted src (for agg)}
__global__ __launch_bounds__(256) void dst_scatter(const int* __restrict__ bdst, const int* __restrict__ bsrc,
                                                   int* __restrict__ cursor, int* __restrict__ eid,
                                                   int* __restrict__ ssrc) {
    int i = blockIdx.x * 256 + threadIdx.x;
    if (i >= N_EDGES) return;
    int d = bdst[i];
    int p = atomicAdd(&cursor[d], 1);
    eid[p] = i;
    ssrc[p] = bsrc[i];
}

// ---------- attention over relation r's bucket only ----------
__global__ __launch_bounds__(256) void attr_bucket(const bf16* __restrict__ projR, const float* __restrict__ rel,
                                                   const int* __restrict__ bsrc, const int* __restrict__ bdst,
                                                   const int* __restrict__ bptr, int r, float* __restrict__ att) {
    int lane = threadIdx.x & 63;
    int wid = blockIdx.x * 4 + (threadIdx.x >> 6);
    int nw = gridDim.x * 4;
    int b0 = bptr[r], b1 = bptr[r + 1];
    float rl = rel[r * 64 + lane];
    for (int i = b0 + wid; i < b1; i += nw) {
        int s = bsrc[i], d = bdst[i];
        float tt = (float)projR[(size_t)s * 64 + lane];
        float hh = (float)projR[(size_t)d * 64 + lane];
        float z = hh + rl;
        float ez = __expf(2.f * z);          // tanh(z) = 1 - 2/(e^{2z}+1), saturates safely
        float v = tt * (1.f - 2.f / (ez + 1.f));
#pragma unroll
        for (int o = 1; o < 64; o <<= 1) v += __shfl_xor(v, o);
        if (lane == 0) att[i] = v;
    }
}

// ---------- per-dst softmax (att gathered via eid, w dense in dst-CSR order) ----------
__global__ __launch_bounds__(256) void softmax_kernel(const int* __restrict__ row_ptr, const int* __restrict__ eid,
                                                      const float* __restrict__ att, float* __restrict__ w) {
    int node = blockIdx.x * 4 + (threadIdx.x >> 6);
    if (node >= N_ENT) return;
    int lane = threadIdx.x & 63;
    int r0 = row_ptr[node], r1 = row_ptr[node + 1];
    if (r0 >= r1) return;
    float m = -__builtin_inff();
    for (int k = r0 + lane; k < r1; k += 64) m = fmaxf(m, att[eid[k]]);
#pragma unroll
    for (int o = 1; o < 64; o <<= 1) m = fmaxf(m, __shfl_xor(m, o));
    float s = 0.f;
    for (int k = r0 + lane; k < r1; k += 64) s += __expf(att[eid[k]] - m);
#pragma unroll
    for (int o = 1; o < 64; o <<= 1) s += __shfl_xor(s, o);
    float inv = (s > 0.f) ? 1.f / s : 0.f;
    for (int k = r0 + lane; k < r1; k += 64) w[k] = __expf(att[eid[k]] - m) * inv;
}

// ---------- aggregation, 4-edge MLP unroll: aggb[n][j] = (bf16) sum_k w[k]*feat[ssrc[k]][j] ----------
template <typename FT>
__global__ __launch_bounds__(256) void agg_kernel(const int* __restrict__ row_ptr, const int* __restrict__ ssrc,
                                                  const float* __restrict__ w, const FT* __restrict__ feat,
                                                  bf16* __restrict__ aggb) {
    int node = blockIdx.x * 4 + (threadIdx.x >> 6);
    if (node >= N_ENT) return;
    int lane = threadIdx.x & 63;
    int r0 = row_ptr[node], r1 = row_ptr[node + 1];
    float acc = 0.f;
    int k = r0;
    for (; k + 4 <= r1; k += 4) {
        int s0 = ssrc[k], s1 = ssrc[k + 1], s2 = ssrc[k + 2], s3 = ssrc[k + 3];
        float w0 = w[k], w1 = w[k + 1], w2 = w[k + 2], w3 = w[k + 3];
        float f0 = (float)feat[(size_t)s0 * 64 + lane];
        float f1 = (float)feat[(size_t)s1 * 64 + lane];
        float f2 = (float)feat[(size_t)s2 * 64 + lane];
        float f3 = (float)feat[(size_t)s3 * 64 + lane];
        acc += w0 * f0; acc += w1 * f1; acc += w2 * f2; acc += w3 * f3;
    }
    for (; k < r1; ++k) acc += w[k] * (float)feat[(size_t)ssrc[k] * 64 + lane];
    aggb[(size_t)node * 64 + lane] = (bf16)acc;
}

// ---------- layer 1: h1 = lrelu((h0*agg) @ W0); out[:,0:64]=h0; out[:,64:128]=l2n(h1) ----------
__global__ __launch_bounds__(256) void transform1_kernel(const float* __restrict__ ent, const bf16* __restrict__ aggb,
                                                         const float* __restrict__ W0, bf16* __restrict__ h1b,
                                                         float* __restrict__ out) {
    __shared__ float Ws[64 * 65];
    int t = threadIdx.x;
    for (int idx = t; idx < 4096; idx += 256) { int d = idx >> 6, j = idx & 63; Ws[d * 65 + j] = W0[idx]; }
    __syncthreads();
    int node = blockIdx.x * 4 + (t >> 6);
    if (node >= N_ENT) return;
    int j = t & 63;
    float h0v = ent[(size_t)node * 64 + j];
    float x = h0v * (float)aggb[(size_t)node * 64 + j];
    float acc = 0.f;
#pragma unroll
    for (int d = 0; d < 64; ++d) acc += __shfl(x, d) * Ws[d * 65 + j];
    float h1v = acc > 0.f ? acc : 0.01f * acc;
    h1b[(size_t)node * 64 + j] = (bf16)h1v;
    float ss = h1v * h1v;
#pragma unroll
    for (int o = 1; o < 64; o <<= 1) ss += __shfl_xor(ss, o);
    float inv = 1.f / fmaxf(sqrtf(ss), 1e-12f);
    out[(size_t)node * OUT_STRIDE + j] = h0v;
    out[(size_t)node * OUT_STRIDE + 64 + j] = h1v * inv;
}

// ---------- layer 2: h2 = lrelu((h1*agg2) @ W1); out[:,128:160]=l2n(h2) ----------
__global__ __launch_bounds__(256) void transform2_kernel(const bf16* __restrict__ h1b, const bf16* __restrict__ aggb,
                                                         const float* __restrict__ W1, float* __restrict__ out) {
    __shared__ float Ws[64 * 33];
    int t = threadIdx.x;
    for (int idx = t; idx < 2048; idx += 256) { int d = idx >> 5, j = idx & 31; Ws[d * 33 + j] = W1[idx]; }
    __syncthreads();
    int node = blockIdx.x * 4 + (t >> 6);
    if (node >= N_ENT) return;
    int j = t & 63;
    float x = (float)h1b[(size_t)node * 64 + j] * (float)aggb[(size_t)node * 64 + j];
    int base = j & 32, jj = j & 31;
    float acc = 0.f;
#pragma unroll
    for (int i = 0; i < 32; ++i) acc += __shfl(x, base + i) * Ws[(base + i) * 33 + jj];
    acc += __shfl_xor(acc, 32);
    float h2 = acc > 0.f ? acc : 0.01f * acc;
    float ss = h2 * h2;
#pragma unroll
    for (int o = 1; o < 32; o <<= 1) ss += __shfl_xor(ss, o);
    float inv = 1.f / fmaxf(sqrtf(ss), 1e-12f);
    if (j < 32) out[(size_t)node * OUT_STRIDE + 128 + jj] = h2 * inv;
}

extern "C" void kernel_launch(void* const* d_in, const int* in_sizes, int n_in,
                              void* d_out, int out_size, void* d_ws, size_t ws_size,
                              hipStream_t stream) {
    const float* ent = (const float*)d_in[0];
    const float* rel = (const float*)d_in[1];
    const float* W_R = (const float*)d_in[2];
    const float* W0  = (const float*)d_in[3];
    const float* W1  = (const float*)d_in[4];
    const int*   src = (const int*)d_in[5];
    const int*   dst = (const int*)d_in[6];
    const int*   ety = (const int*)d_in[7];
    float* out = (float*)d_out;

    char* ws = (char*)d_ws;
    size_t off = 0;
    auto take = [&](size_t bytes) -> char* {
        char* p = ws + off;
        off += (bytes + 255) & ~(size_t)255;
        return p;
    };
    int*   bsrc  = (int*)take((size_t)N_EDGES * 4);       // 6.4 MB  src in bucket order
    int*   eid   = (int*)take((size_t)N_EDGES * 4);       // 6.4 MB  dst-CSR slot -> bucket index
    int*   ssrc  = (int*)take((size_t)N_EDGES * 4);       // 6.4 MB  src in dst-CSR order
    float* w     = (float*)take((size_t)N_EDGES * 4);     // 6.4 MB  softmax weights (CSR order)
    // cnt and cnt16 in ONE take so they are truly contiguous for the fused zero
    // (R6 bug: N_ENT*4=400000 is NOT a 256 multiple -> take() pad left cnt16 poisoned -> OOB abort)
    int*   cnt   = (int*)take((size_t)(N_ENT + 16) * 4);
    int*   cnt16 = cnt + N_ENT;
    int*   bptr  = (int*)take(68);
    int*   cur16 = (int*)take(64);
    int*   rowp  = (int*)take((size_t)(N_ENT + 1) * 4);
    int*   cur   = (int*)take((size_t)N_ENT * 4);
    int*   part  = (int*)take(NCHUNK * 4);
    int*   pbase = (int*)take(NCHUNK * 4);
    // overlay region A: {att 6.4 | bdst 6.4} -> h1b 12.8 (att dead after softmax, bdst dead after attr loop;
    //                    att size 6400000 IS a 256 multiple -> bdst contiguous after att)
    float* att   = (float*)take((size_t)N_EDGES * 4);
    int*   bdst  = (int*)take((size_t)N_EDGES * 4);
    bf16*  h1b   = (bf16*)att;
    // overlay region B: projR 12.8 -> aggb (projR dead after attr loop)
    bf16*  projR = (bf16*)take((size_t)N_ENT * 64 * 2);
    bf16*  aggb  = projR;
    size_t needed = off;    // ~52.7 MB

    if (needed > ws_size) {
        zero_out_kernel<<<512, 256, 0, stream>>>(out, out_size);
        return;
    }

    // zero cnt + cnt16 (single allocation, exactly N_ENT+16 ints)
    zero_kernel<<<512, 256, 0, stream>>>(cnt, N_ENT + 16);

    hist_kernel<<<N_EDGES / 256, 256, 0, stream>>>(dst, ety, cnt, cnt16);
    bucket_scan<<<1, 64, 0, stream>>>(cnt16, bptr, cur16);
    bucket_scatter<<<N_EDGES / 256, 256, 0, stream>>>(src, dst, ety, cur16, bsrc, bdst);
    scan1<<<NCHUNK, 256, 0, stream>>>(cnt, part);
    scan2<<<1, 64, 0, stream>>>(part, pbase);
    scan3<<<NCHUNK, 256, 0, stream>>>(cnt, pbase, rowp, cur);
    dst_scatter<<<N_EDGES / 256, 256, 0, stream>>>(bdst, bsrc, cur, eid, ssrc);

    for (int r = 0; r < N_REL; ++r) {
        projr_simple<<<(N_ENT + 15) / 16, 256, 0, stream>>>(ent, W_R + (size_t)r * 4096, projR);
        attr_bucket<<<1024, 256, 0, stream>>>(projR, rel, bsrc, bdst, bptr, r, att);
    }

    softmax_kernel<<<N_ENT / 4, 256, 0, stream>>>(rowp, eid, att, w);
    agg_kernel<float><<<N_ENT / 4, 256, 0, stream>>>(rowp, ssrc, w, ent, aggb);
    transform1_kernel<<<N_ENT / 4, 256, 0, stream>>>(ent, aggb, W0, h1b, out);
    agg_kernel<bf16><<<N_ENT / 4, 256, 0, stream>>>(rowp, ssrc, w, h1b, aggb);
    transform2_kernel<<<N_ENT / 4, 256, 0, stream>>>(h1b, aggb, W1, out);
}

// Round 8
// 1318.245 us; speedup vs baseline: 3.6972x; 1.9818x over previous
//
#include <hip/hip_runtime.h>
#include <hip/hip_bf16.h>
#include <math.h>

typedef __bf16 bf16;
typedef __bf16 bf16x8 __attribute__((ext_vector_type(8)));
typedef __bf16 bf16x4 __attribute__((ext_vector_type(4)));
typedef float f32x4 __attribute__((ext_vector_type(4)));

#define N_ENT   100000
#define N_REL   16
#define N_EDGES 1600000
#define OUT_STRIDE 160
#define NCHUNK  98   // ceil(N_ENT/1024)

// ---------- zero an int region (grid-stride) ----------
__global__ __launch_bounds__(256) void zero_kernel(int* __restrict__ p, int n) {
    int i = blockIdx.x * 256 + threadIdx.x;
    int stride = gridDim.x * 256;
    for (; i < n; i += stride) p[i] = 0;
}

// ---------- ws-too-small tripwire: all-zero output (absmax ~0.9375 signature) ----------
__global__ __launch_bounds__(256) void zero_out_kernel(float* __restrict__ out, int n) {
    int i = blockIdx.x * 256 + threadIdx.x;
    int stride = gridDim.x * 256;
    for (; i < n; i += stride) out[i] = 0.f;
}

// ---------- MFMA projection: projR[n][j] = (bf16) sum_d ent[n][d] * Wr[d][j] ----------
// 16x16x32 bf16. A = Wr^T (A[j][d]), B = ent^T (B[d][n]).
// A frag: A[m=lane&15][k=q*8+i]; B frag: B[k=q*8+i][n=lane&15]; C/D: col=lane&15, row=q*4+i (m89).
__global__ __launch_bounds__(256) void projr_mfma(const float* __restrict__ ent,
                                                  const float* __restrict__ Wr,
                                                  bf16* __restrict__ projR) {
    __shared__ bf16 WT[64 * 72];  // WT[j][d] = Wr[d][j]; stride 72 (16B-aligned rows, conflict-free-ish)
    const int tid = threadIdx.x;
    for (int idx = tid; idx < 4096; idx += 256) {
        int d = idx >> 6, j = idx & 63;
        WT[j * 72 + d] = (bf16)Wr[idx];
    }
    __syncthreads();
    const int wave = tid >> 6, lane = tid & 63;
    const int m = lane & 15, q = lane >> 4;
    bf16x8 af[4][2];
#pragma unroll
    for (int mt = 0; mt < 4; ++mt)
#pragma unroll
        for (int ks = 0; ks < 2; ++ks)
            af[mt][ks] = *(const bf16x8*)&WT[(mt * 16 + m) * 72 + ks * 32 + q * 8];

#pragma unroll
    for (int it = 0; it < 4; ++it) {
        int n0 = blockIdx.x * 256 + it * 64 + wave * 16;
        if (n0 >= N_ENT) continue;   // N_ENT % 16 == 0 -> tiles all-or-nothing
        const float* ep = ent + (size_t)(n0 + m) * 64;
        float4 a0 = *(const float4*)(ep + q * 8);
        float4 a1 = *(const float4*)(ep + q * 8 + 4);
        float4 a2 = *(const float4*)(ep + 32 + q * 8);
        float4 a3 = *(const float4*)(ep + 32 + q * 8 + 4);
        bf16x8 b0, b1;
        b0[0]=(bf16)a0.x; b0[1]=(bf16)a0.y; b0[2]=(bf16)a0.z; b0[3]=(bf16)a0.w;
        b0[4]=(bf16)a1.x; b0[5]=(bf16)a1.y; b0[6]=(bf16)a1.z; b0[7]=(bf16)a1.w;
        b1[0]=(bf16)a2.x; b1[1]=(bf16)a2.y; b1[2]=(bf16)a2.z; b1[3]=(bf16)a2.w;
        b1[4]=(bf16)a3.x; b1[5]=(bf16)a3.y; b1[6]=(bf16)a3.z; b1[7]=(bf16)a3.w;
        bf16* op = projR + (size_t)(n0 + m) * 64 + q * 4;
#pragma unroll
        for (int mt = 0; mt < 4; ++mt) {
            f32x4 acc = {0.f, 0.f, 0.f, 0.f};
            acc = __builtin_amdgcn_mfma_f32_16x16x32_bf16(af[mt][0], b0, acc, 0, 0, 0);
            acc = __builtin_amdgcn_mfma_f32_16x16x32_bf16(af[mt][1], b1, acc, 0, 0, 0);
            bf16x4 o;
#pragma unroll
            for (int i = 0; i < 4; ++i) o[i] = (bf16)acc[i];
            *(bf16x4*)(op + mt * 16) = o;   // projR[n0+m][mt*16 + q*4 + i]
        }
    }
}

// ---------- fused histograms: dst-degree (global) + etype bins (LDS-staged) ----------
__global__ __launch_bounds__(256) void hist_kernel(const int* __restrict__ dst, const int* __restrict__ ety,
                                                   int* __restrict__ cnt, int* __restrict__ cnt16) {
    __shared__ int h16[16];
    int t = threadIdx.x;
    if (t < 16) h16[t] = 0;
    __syncthreads();
    int e = blockIdx.x * 256 + t;
    if (e < N_EDGES) {
        atomicAdd(&cnt[dst[e]], 1);
        atomicAdd(&h16[ety[e]], 1);
    }
    __syncthreads();
    if (t < 16 && h16[t] > 0) atomicAdd(&cnt16[t], h16[t]);
}

__global__ void bucket_scan(const int* __restrict__ cnt16, int* __restrict__ bptr, int* __restrict__ cur16) {
    if (threadIdx.x == 0) {
        int s = 0;
        for (int r = 0; r < N_REL; ++r) { bptr[r] = s; cur16[r] = s; s += cnt16[r]; }
        bptr[N_REL] = s;
    }
}

// ballot-rank scatter into 16 etype buckets (block-level reservation on 16 counters)
__global__ __launch_bounds__(256) void bucket_scatter(const int* __restrict__ src, const int* __restrict__ dst,
                                                      const int* __restrict__ ety, int* __restrict__ cur16,
                                                      int* __restrict__ bsrc, int* __restrict__ bdst) {
    __shared__ int whist[4][16];
    __shared__ int wbase[4][16];
    __shared__ int bbase[16];
    int t = threadIdx.x, wave = t >> 6, lane = t & 63;
    int e = blockIdx.x * 256 + t;
    int b = (e < N_EDGES) ? ety[e] : -1;
    unsigned long long ltmask = (1ull << lane) - 1ull;
    int rank = 0;
#pragma unroll
    for (int r = 0; r < 16; ++r) {
        unsigned long long mk = __ballot(b == r);
        if (b == r) rank = __popcll(mk & ltmask);
        if (lane == r) whist[wave][r] = __popcll(mk);
    }
    __syncthreads();
    if (t < 16) {
        int s0 = whist[0][t], s1 = whist[1][t], s2 = whist[2][t], s3 = whist[3][t];
        bbase[t] = atomicAdd(&cur16[t], s0 + s1 + s2 + s3);
        wbase[0][t] = 0; wbase[1][t] = s0; wbase[2][t] = s0 + s1; wbase[3][t] = s0 + s1 + s2;
    }
    __syncthreads();
    if (b >= 0) {
        int pos = bbase[b] + wbase[wave][b] + rank;
        bsrc[pos] = src[e];
        bdst[pos] = dst[e];
    }
}

// ---------- dst-CSR scans ----------
__global__ __launch_bounds__(256) void scan1(const int* __restrict__ cnt, int* __restrict__ part) {
    __shared__ int sh[256];
    int bIdx = blockIdx.x, t = threadIdx.x;
    int i0 = bIdx * 1024 + t * 4;
    int s = 0;
#pragma unroll
    for (int u = 0; u < 4; ++u) { int i = i0 + u; if (i < N_ENT) s += cnt[i]; }
    sh[t] = s; __syncthreads();
    for (int o = 128; o > 0; o >>= 1) { if (t < o) sh[t] += sh[t + o]; __syncthreads(); }
    if (t == 0) part[bIdx] = sh[0];
}

__global__ void scan2(const int* __restrict__ part, int* __restrict__ pbase) {
    if (threadIdx.x == 0) {
        int s = 0;
        for (int i = 0; i < NCHUNK; ++i) { pbase[i] = s; s += part[i]; }
    }
}

__global__ __launch_bounds__(256) void scan3(const int* __restrict__ cnt, const int* __restrict__ pbase,
                                             int* __restrict__ row_ptr, int* __restrict__ cursor) {
    __shared__ int sh[256];
    int bIdx = blockIdx.x, t = threadIdx.x;
    int i0 = bIdx * 1024 + t * 4;
    int c[4]; int s = 0;
#pragma unroll
    for (int u = 0; u < 4; ++u) { c[u] = (i0 + u < N_ENT) ? cnt[i0 + u] : 0; s += c[u]; }
    sh[t] = s; __syncthreads();
    for (int o = 1; o < 256; o <<= 1) {
        int add = (t >= o) ? sh[t - o] : 0;
        __syncthreads();
        sh[t] += add;
        __syncthreads();
    }
    int run = pbase[bIdx] + sh[t] - s;
#pragma unroll
    for (int u = 0; u < 4; ++u) {
        if (i0 + u < N_ENT) { row_ptr[i0 + u] = run; cursor[i0 + u] = run; run += c[u]; }
    }
    if (bIdx == 0 && t == 0) row_ptr[N_ENT] = N_EDGES;
}

// dst-CSR slot p <- packed {bucket index i, src} as ONE 8B write (halves scatter line-touches)
__global__ __launch_bounds__(256) void dst_scatter(const int* __restrict__ bdst, const int* __restrict__ bsrc,
                                                   int* __restrict__ cursor, int2* __restrict__ pair) {
    int i = blockIdx.x * 256 + threadIdx.x;
    if (i >= N_EDGES) return;
    int d = bdst[i];
    int p = atomicAdd(&cursor[d], 1);
    pair[p] = make_int2(i, bsrc[i]);
}

// ---------- attention over relation r's bucket only ----------
__global__ __launch_bounds__(256) void attr_bucket(const bf16* __restrict__ projR, const float* __restrict__ rel,
                                                   const int* __restrict__ bsrc, const int* __restrict__ bdst,
                                                   const int* __restrict__ bptr, int r, float* __restrict__ att) {
    int lane = threadIdx.x & 63;
    int wid = blockIdx.x * 4 + (threadIdx.x >> 6);
    int nw = gridDim.x * 4;
    int b0 = bptr[r], b1 = bptr[r + 1];
    float rl = rel[r * 64 + lane];
    for (int i = b0 + wid; i < b1; i += nw) {
        int s = bsrc[i], d = bdst[i];
        float tt = (float)projR[(size_t)s * 64 + lane];
        float hh = (float)projR[(size_t)d * 64 + lane];
        float z = hh + rl;
        float ez = __expf(2.f * z);          // tanh(z) = 1 - 2/(e^{2z}+1), saturates safely
        float v = tt * (1.f - 2.f / (ez + 1.f));
#pragma unroll
        for (int o = 1; o < 64; o <<= 1) v += __shfl_xor(v, o);
        if (lane == 0) att[i] = v;
    }
}

// ---------- per-dst softmax (att gathered via pair.x, w dense in dst-CSR order) ----------
__global__ __launch_bounds__(256) void softmax_kernel(const int* __restrict__ row_ptr, const int2* __restrict__ pair,
                                                      const float* __restrict__ att, float* __restrict__ w) {
    int node = blockIdx.x * 4 + (threadIdx.x >> 6);
    if (node >= N_ENT) return;
    int lane = threadIdx.x & 63;
    int r0 = row_ptr[node], r1 = row_ptr[node + 1];
    if (r0 >= r1) return;
    float m = -__builtin_inff();
    for (int k = r0 + lane; k < r1; k += 64) m = fmaxf(m, att[pair[k].x]);
#pragma unroll
    for (int o = 1; o < 64; o <<= 1) m = fmaxf(m, __shfl_xor(m, o));
    float s = 0.f;
    for (int k = r0 + lane; k < r1; k += 64) s += __expf(att[pair[k].x] - m);
#pragma unroll
    for (int o = 1; o < 64; o <<= 1) s += __shfl_xor(s, o);
    float inv = (s > 0.f) ? 1.f / s : 0.f;
    for (int k = r0 + lane; k < r1; k += 64) w[k] = __expf(att[pair[k].x] - m) * inv;
}

// ---------- aggregation, 4-edge MLP unroll: aggb[n][j] = (bf16) sum_k w[k]*feat[pair[k].y][j] ----------
template <typename FT>
__global__ __launch_bounds__(256) void agg_kernel(const int* __restrict__ row_ptr, const int2* __restrict__ pair,
                                                  const float* __restrict__ w, const FT* __restrict__ feat,
                                                  bf16* __restrict__ aggb) {
    int node = blockIdx.x * 4 + (threadIdx.x >> 6);
    if (node >= N_ENT) return;
    int lane = threadIdx.x & 63;
    int r0 = row_ptr[node], r1 = row_ptr[node + 1];
    float acc = 0.f;
    int k = r0;
    for (; k + 4 <= r1; k += 4) {
        int s0 = pair[k].y, s1 = pair[k + 1].y, s2 = pair[k + 2].y, s3 = pair[k + 3].y;
        float w0 = w[k], w1 = w[k + 1], w2 = w[k + 2], w3 = w[k + 3];
        float f0 = (float)feat[(size_t)s0 * 64 + lane];
        float f1 = (float)feat[(size_t)s1 * 64 + lane];
        float f2 = (float)feat[(size_t)s2 * 64 + lane];
        float f3 = (float)feat[(size_t)s3 * 64 + lane];
        acc += w0 * f0; acc += w1 * f1; acc += w2 * f2; acc += w3 * f3;
    }
    for (; k < r1; ++k) acc += w[k] * (float)feat[(size_t)pair[k].y * 64 + lane];
    aggb[(size_t)node * 64 + lane] = (bf16)acc;
}

// ---------- layer 1: h1 = lrelu((h0*agg) @ W0); out[:,0:64]=h0; out[:,64:128]=l2n(h1) ----------
__global__ __launch_bounds__(256) void transform1_kernel(const float* __restrict__ ent, const bf16* __restrict__ aggb,
                                                         const float* __restrict__ W0, bf16* __restrict__ h1b,
                                                         float* __restrict__ out) {
    __shared__ float Ws[64 * 65];
    int t = threadIdx.x;
    for (int idx = t; idx < 4096; idx += 256) { int d = idx >> 6, j = idx & 63; Ws[d * 65 + j] = W0[idx]; }
    __syncthreads();
    int node = blockIdx.x * 4 + (t >> 6);
    if (node >= N_ENT) return;
    int j = t & 63;
    float h0v = ent[(size_t)node * 64 + j];
    float x = h0v * (float)aggb[(size_t)node * 64 + j];
    float acc = 0.f;
#pragma unroll
    for (int d = 0; d < 64; ++d) acc += __shfl(x, d) * Ws[d * 65 + j];
    float h1v = acc > 0.f ? acc : 0.01f * acc;
    h1b[(size_t)node * 64 + j] = (bf16)h1v;
    float ss = h1v * h1v;
#pragma unroll
    for (int o = 1; o < 64; o <<= 1) ss += __shfl_xor(ss, o);
    float inv = 1.f / fmaxf(sqrtf(ss), 1e-12f);
    out[(size_t)node * OUT_STRIDE + j] = h0v;
    out[(size_t)node * OUT_STRIDE + 64 + j] = h1v * inv;
}

// ---------- layer 2: h2 = lrelu((h1*agg2) @ W1); out[:,128:160]=l2n(h2) ----------
__global__ __launch_bounds__(256) void transform2_kernel(const bf16* __restrict__ h1b, const bf16* __restrict__ aggb,
                                                         const float* __restrict__ W1, float* __restrict__ out) {
    __shared__ float Ws[64 * 33];
    int t = threadIdx.x;
    for (int idx = t; idx < 2048; idx += 256) { int d = idx >> 5, j = idx & 31; Ws[d * 33 + j] = W1[idx]; }
    __syncthreads();
    int node = blockIdx.x * 4 + (t >> 6);
    if (node >= N_ENT) return;
    int j = t & 63;
    float x = (float)h1b[(size_t)node * 64 + j] * (float)aggb[(size_t)node * 64 + j];
    int base = j & 32, jj = j & 31;
    float acc = 0.f;
#pragma unroll
    for (int i = 0; i < 32; ++i) acc += __shfl(x, base + i) * Ws[(base + i) * 33 + jj];
    acc += __shfl_xor(acc, 32);
    float h2 = acc > 0.f ? acc : 0.01f * acc;
    float ss = h2 * h2;
#pragma unroll
    for (int o = 1; o < 32; o <<= 1) ss += __shfl_xor(ss, o);
    float inv = 1.f / fmaxf(sqrtf(ss), 1e-12f);
    if (j < 32) out[(size_t)node * OUT_STRIDE + 128 + jj] = h2 * inv;
}

extern "C" void kernel_launch(void* const* d_in, const int* in_sizes, int n_in,
                              void* d_out, int out_size, void* d_ws, size_t ws_size,
                              hipStream_t stream) {
    const float* ent = (const float*)d_in[0];
    const float* rel = (const float*)d_in[1];
    const float* W_R = (const float*)d_in[2];
    const float* W0  = (const float*)d_in[3];
    const float* W1  = (const float*)d_in[4];
    const int*   src = (const int*)d_in[5];
    const int*   dst = (const int*)d_in[6];
    const int*   ety = (const int*)d_in[7];
    float* out = (float*)d_out;

    char* ws = (char*)d_ws;
    size_t off = 0;
    auto take = [&](size_t bytes) -> char* {
        char* p = ws + off;
        off += (bytes + 255) & ~(size_t)255;
        return p;
    };
    int*   bsrc  = (int*)take((size_t)N_EDGES * 4);       // 6.4 MB  src in bucket order
    int2*  pair  = (int2*)take((size_t)N_EDGES * 8);      // 12.8 MB {bucket idx, src} in dst-CSR order
    float* w     = (float*)take((size_t)N_EDGES * 4);     // 6.4 MB  softmax weights (CSR order)
    // cnt and cnt16 in ONE take (contiguity for the fused zero; N_ENT*4 is not a 256 multiple)
    int*   cnt   = (int*)take((size_t)(N_ENT + 16) * 4);
    int*   cnt16 = cnt + N_ENT;
    int*   bptr  = (int*)take(68);
    int*   cur16 = (int*)take(64);
    int*   rowp  = (int*)take((size_t)(N_ENT + 1) * 4);
    int*   cur   = (int*)take((size_t)N_ENT * 4);
    int*   part  = (int*)take(NCHUNK * 4);
    int*   pbase = (int*)take(NCHUNK * 4);
    // overlay region A: {att 6.4 | bdst 6.4} -> h1b 12.8 (att dead after softmax, bdst dead after attr loop;
    //                    att size 6400000 IS a 256 multiple -> bdst contiguous after att)
    float* att   = (float*)take((size_t)N_EDGES * 4);
    int*   bdst  = (int*)take((size_t)N_EDGES * 4);
    bf16*  h1b   = (bf16*)att;
    // overlay region B: projR 12.8 -> aggb (projR dead after attr loop)
    bf16*  projR = (bf16*)take((size_t)N_ENT * 64 * 2);
    bf16*  aggb  = projR;
    size_t needed = off;    // ~59 MB

    if (needed > ws_size) {
        zero_out_kernel<<<512, 256, 0, stream>>>(out, out_size);
        return;
    }

    // zero cnt + cnt16 (single allocation, exactly N_ENT+16 ints)
    zero_kernel<<<512, 256, 0, stream>>>(cnt, N_ENT + 16);

    hist_kernel<<<N_EDGES / 256, 256, 0, stream>>>(dst, ety, cnt, cnt16);
    bucket_scan<<<1, 64, 0, stream>>>(cnt16, bptr, cur16);
    bucket_scatter<<<N_EDGES / 256, 256, 0, stream>>>(src, dst, ety, cur16, bsrc, bdst);
    scan1<<<NCHUNK, 256, 0, stream>>>(cnt, part);
    scan2<<<1, 64, 0, stream>>>(part, pbase);
    scan3<<<NCHUNK, 256, 0, stream>>>(cnt, pbase, rowp, cur);
    dst_scatter<<<N_EDGES / 256, 256, 0, stream>>>(bdst, bsrc, cur, pair);

    for (int r = 0; r < N_REL; ++r) {
        projr_mfma<<<(N_ENT + 255) / 256, 256, 0, stream>>>(ent, W_R + (size_t)r * 4096, projR);
        attr_bucket<<<1024, 256, 0, stream>>>(projR, rel, bsrc, bdst, bptr, r, att);
    }

    softmax_kernel<<<N_ENT / 4, 256, 0, stream>>>(rowp, pair, att, w);
    agg_kernel<float><<<N_ENT / 4, 256, 0, stream>>>(rowp, pair, w, ent, aggb);
    transform1_kernel<<<N_ENT / 4, 256, 0, stream>>>(ent, aggb, W0, h1b, out);
    agg_kernel<bf16><<<N_ENT / 4, 256, 0, stream>>>(rowp, pair, w, h1b, aggb);
    transform2_kernel<<<N_ENT / 4, 256, 0, stream>>>(h1b, aggb, W1, out);
}

// Round 9
// 867.783 us; speedup vs baseline: 5.6165x; 1.5191x over previous
//
#include <hip/hip_runtime.h>
#include <hip/hip_bf16.h>
#include <math.h>

typedef __bf16 bf16;
typedef __bf16 bf16x8 __attribute__((ext_vector_type(8)));
typedef float f32x4 __attribute__((ext_vector_type(4)));

#define N_ENT   100000
#define N_REL   16
#define N_EDGES 1600000
#define E_PAD   (N_EDGES + 256)   // bucket arrays padded (<=16 pad slots per relation)
#define OUT_STRIDE 160
#define NCHUNK  98   // ceil(N_ENT/1024)

// ---------- fill an int region (grid-stride) ----------
__global__ __launch_bounds__(256) void fill_kernel(int* __restrict__ p, int v, int n) {
    int i = blockIdx.x * 256 + threadIdx.x;
    int stride = gridDim.x * 256;
    for (; i < n; i += stride) p[i] = v;
}

// ---------- ws-too-small tripwire ----------
__global__ __launch_bounds__(256) void zero_out_kernel(float* __restrict__ out, int n) {
    int i = blockIdx.x * 256 + threadIdx.x;
    int stride = gridDim.x * 256;
    for (; i < n; i += stride) out[i] = 0.f;
}

// ---------- etype histogram (LDS-staged only) ----------
__global__ __launch_bounds__(256) void hist16_kernel(const int* __restrict__ ety, int* __restrict__ cnt16) {
    __shared__ int h16[16];
    int t = threadIdx.x;
    if (t < 16) h16[t] = 0;
    __syncthreads();
    int e = blockIdx.x * 256 + t;
    if (e < N_EDGES) atomicAdd(&h16[ety[e]], 1);
    __syncthreads();
    if (t < 16 && h16[t] > 0) atomicAdd(&cnt16[t], h16[t]);
}

// padded bucket offsets (each bucket start multiple of 16)
__global__ void bucket_scan(const int* __restrict__ cnt16, int* __restrict__ bptr16, int* __restrict__ cur16) {
    if (threadIdx.x == 0) {
        int s = 0;
        for (int r = 0; r < N_REL; ++r) {
            bptr16[r] = s; cur16[r] = s;
            s += (cnt16[r] + 15) & ~15;
        }
        bptr16[N_REL] = s;
    }
}

// ballot-rank scatter into padded etype buckets; also dst-degree histogram (fused)
__global__ __launch_bounds__(256) void bucket_scatter(const int* __restrict__ src, const int* __restrict__ dst,
                                                      const int* __restrict__ ety, int* __restrict__ cur16,
                                                      int* __restrict__ bsrc, int* __restrict__ bdst,
                                                      int* __restrict__ cnt) {
    __shared__ int whist[4][16];
    __shared__ int wbase[4][16];
    __shared__ int bbase[16];
    int t = threadIdx.x, wave = t >> 6, lane = t & 63;
    int e = blockIdx.x * 256 + t;
    int b = -1, d = 0;
    if (e < N_EDGES) {
        b = ety[e];
        d = dst[e];
        atomicAdd(&cnt[d], 1);
    }
    unsigned long long ltmask = (1ull << lane) - 1ull;
    int rank = 0;
#pragma unroll
    for (int r = 0; r < 16; ++r) {
        unsigned long long mk = __ballot(b == r);
        if (b == r) rank = __popcll(mk & ltmask);
        if (lane == r) whist[wave][r] = __popcll(mk);
    }
    __syncthreads();
    if (t < 16) {
        int s0 = whist[0][t], s1 = whist[1][t], s2 = whist[2][t], s3 = whist[3][t];
        bbase[t] = atomicAdd(&cur16[t], s0 + s1 + s2 + s3);
        wbase[0][t] = 0; wbase[1][t] = s0; wbase[2][t] = s0 + s1; wbase[3][t] = s0 + s1 + s2;
    }
    __syncthreads();
    if (b >= 0) {
        int pos = bbase[b] + wbase[wave][b] + rank;
        bsrc[pos] = src[e];
        bdst[pos] = d;
    }
}

// ---------- fused per-edge MFMA attention over relation r = blockIdx.y ----------
// Per 16-edge group g: T = ENT[src rows] @ W_r (16x64), H = ENT[dst rows] @ W_r,
// att[e] = sum_n T[e][n]*tanh(H[e][n]+rel_r[n]).
// A-frag: A[m=lane&15][k=q*8+j] (edge rows, gathered). B-frag: B[k=q*8+j][n=lane&15]
// from LDS WT[n][k] (stride 72). C/D: col=lane&15 = n, row=q*4+i = edge (m89).
__global__ __launch_bounds__(256) void fused_att(const float* __restrict__ ent, const float* __restrict__ W_R,
                                                 const float* __restrict__ rel, const int* __restrict__ bsrc,
                                                 const int* __restrict__ bdst, const int* __restrict__ bptr16,
                                                 float* __restrict__ att) {
    __shared__ bf16 WT[64 * 72];     // WT[n][k] = W_r[k][n]
    __shared__ float relS[64];
    const int r = blockIdx.y;
    const int t = threadIdx.x;
    const float* Wr = W_R + (size_t)r * 4096;
    for (int idx = t; idx < 4096; idx += 256) {
        int k = idx >> 6, n = idx & 63;
        WT[n * 72 + k] = (bf16)Wr[idx];
    }
    if (t < 64) relS[t] = rel[r * 64 + t];
    __syncthreads();

    const int lane = t & 63, m = lane & 15, q = lane >> 4;
    // B-frags (group-invariant): bb[nt][ks] = WT[nt*16+m][ks*32+q*8 ..+7]
    bf16x8 bb[4][2];
#pragma unroll
    for (int nt = 0; nt < 4; ++nt)
#pragma unroll
        for (int ks = 0; ks < 2; ++ks)
            bb[nt][ks] = *(const bf16x8*)&WT[(nt * 16 + m) * 72 + ks * 32 + q * 8];

    int g0 = bptr16[r] >> 4, g1 = bptr16[r + 1] >> 4;
    int wv = blockIdx.x * 4 + (t >> 6);
    int nw = gridDim.x * 4;
    for (int g = g0 + wv; g < g1; g += nw) {
        int sidx = bsrc[g * 16 + m]; if (sidx < 0) sidx = 0;   // pad slots clamped
        int didx = bdst[g * 16 + m]; if (didx < 0) didx = 0;
        const float* sp = ent + (size_t)sidx * 64;
        const float* dp = ent + (size_t)didx * 64;
        bf16x8 as0, as1, ad0, ad1;
        {
            float4 a = *(const float4*)(sp + q * 8), b = *(const float4*)(sp + q * 8 + 4);
            as0[0]=(bf16)a.x; as0[1]=(bf16)a.y; as0[2]=(bf16)a.z; as0[3]=(bf16)a.w;
            as0[4]=(bf16)b.x; as0[5]=(bf16)b.y; as0[6]=(bf16)b.z; as0[7]=(bf16)b.w;
            a = *(const float4*)(sp + 32 + q * 8); b = *(const float4*)(sp + 32 + q * 8 + 4);
            as1[0]=(bf16)a.x; as1[1]=(bf16)a.y; as1[2]=(bf16)a.z; as1[3]=(bf16)a.w;
            as1[4]=(bf16)b.x; as1[5]=(bf16)b.y; as1[6]=(bf16)b.z; as1[7]=(bf16)b.w;
            a = *(const float4*)(dp + q * 8); b = *(const float4*)(dp + q * 8 + 4);
            ad0[0]=(bf16)a.x; ad0[1]=(bf16)a.y; ad0[2]=(bf16)a.z; ad0[3]=(bf16)a.w;
            ad0[4]=(bf16)b.x; ad0[5]=(bf16)b.y; ad0[6]=(bf16)b.z; ad0[7]=(bf16)b.w;
            a = *(const float4*)(dp + 32 + q * 8); b = *(const float4*)(dp + 32 + q * 8 + 4);
            ad1[0]=(bf16)a.x; ad1[1]=(bf16)a.y; ad1[2]=(bf16)a.z; ad1[3]=(bf16)a.w;
            ad1[4]=(bf16)b.x; ad1[5]=(bf16)b.y; ad1[6]=(bf16)b.z; ad1[7]=(bf16)b.w;
        }
        float part0 = 0.f, part1 = 0.f, part2 = 0.f, part3 = 0.f;
#pragma unroll
        for (int nt = 0; nt < 4; ++nt) {
            f32x4 tacc = {0.f, 0.f, 0.f, 0.f};
            tacc = __builtin_amdgcn_mfma_f32_16x16x32_bf16(as0, bb[nt][0], tacc, 0, 0, 0);
            tacc = __builtin_amdgcn_mfma_f32_16x16x32_bf16(as1, bb[nt][1], tacc, 0, 0, 0);
            f32x4 hacc = {0.f, 0.f, 0.f, 0.f};
            hacc = __builtin_amdgcn_mfma_f32_16x16x32_bf16(ad0, bb[nt][0], hacc, 0, 0, 0);
            hacc = __builtin_amdgcn_mfma_f32_16x16x32_bf16(ad1, bb[nt][1], hacc, 0, 0, 0);
            float rl = relS[nt * 16 + m];
#pragma unroll
            for (int i = 0; i < 4; ++i) {
                float z = hacc[i] + rl;
                float ez = __expf(2.f * z);                 // tanh(z) = 1 - 2/(e^{2z}+1)
                float th = 1.f - 2.f / (ez + 1.f);
                float tv = tacc[i] * th;
                if (i == 0) part0 += tv; else if (i == 1) part1 += tv;
                else if (i == 2) part2 += tv; else part3 += tv;
            }
        }
        // reduce over the 16 lanes sharing q (dims); xor<16 stays in group
#pragma unroll
        for (int o = 1; o < 16; o <<= 1) {
            part0 += __shfl_xor(part0, o);
            part1 += __shfl_xor(part1, o);
            part2 += __shfl_xor(part2, o);
            part3 += __shfl_xor(part3, o);
        }
        if (m == 0) {
            float4 v = make_float4(part0, part1, part2, part3);
            *(float4*)&att[g * 16 + q * 4] = v;   // edges g*16 + q*4 + i
        }
    }
}

// ---------- dst-CSR scans ----------
__global__ __launch_bounds__(256) void scan1(const int* __restrict__ cnt, int* __restrict__ part) {
    __shared__ int sh[256];
    int bIdx = blockIdx.x, t = threadIdx.x;
    int i0 = bIdx * 1024 + t * 4;
    int s = 0;
#pragma unroll
    for (int u = 0; u < 4; ++u) { int i = i0 + u; if (i < N_ENT) s += cnt[i]; }
    sh[t] = s; __syncthreads();
    for (int o = 128; o > 0; o >>= 1) { if (t < o) sh[t] += sh[t + o]; __syncthreads(); }
    if (t == 0) part[bIdx] = sh[0];
}

__global__ void scan2(const int* __restrict__ part, int* __restrict__ pbase) {
    if (threadIdx.x == 0) {
        int s = 0;
        for (int i = 0; i < NCHUNK; ++i) { pbase[i] = s; s += part[i]; }
    }
}

__global__ __launch_bounds__(256) void scan3(const int* __restrict__ cnt, const int* __restrict__ pbase,
                                             int* __restrict__ row_ptr, int* __restrict__ cursor) {
    __shared__ int sh[256];
    int bIdx = blockIdx.x, t = threadIdx.x;
    int i0 = bIdx * 1024 + t * 4;
    int c[4]; int s = 0;
#pragma unroll
    for (int u = 0; u < 4; ++u) { c[u] = (i0 + u < N_ENT) ? cnt[i0 + u] : 0; s += c[u]; }
    sh[t] = s; __syncthreads();
    for (int o = 1; o < 256; o <<= 1) {
        int add = (t >= o) ? sh[t - o] : 0;
        __syncthreads();
        sh[t] += add;
        __syncthreads();
    }
    int run = pbase[bIdx] + sh[t] - s;
#pragma unroll
    for (int u = 0; u < 4; ++u) {
        if (i0 + u < N_ENT) { row_ptr[i0 + u] = run; cursor[i0 + u] = run; run += c[u]; }
    }
    if (bIdx == 0 && t == 0) row_ptr[N_ENT] = N_EDGES;
}

// dst-CSR slot p <- packed {src, att} (8B); pads (bdst<0) skipped
__global__ __launch_bounds__(256) void dst_scatter(const int* __restrict__ bdst, const int* __restrict__ bsrc,
                                                   const float* __restrict__ att, int* __restrict__ cursor,
                                                   int2* __restrict__ pair) {
    int i = blockIdx.x * 256 + threadIdx.x;
    if (i >= E_PAD) return;
    int d = bdst[i];
    if (d < 0) return;
    int p = atomicAdd(&cursor[d], 1);
    pair[p] = make_int2(bsrc[i], __float_as_int(att[i]));
}

// ---------- per-dst softmax, fully coalesced; overwrites pair.y with w ----------
__global__ __launch_bounds__(256) void softmax_kernel(const int* __restrict__ row_ptr, int2* __restrict__ pair) {
    int node = blockIdx.x * 4 + (threadIdx.x >> 6);
    if (node >= N_ENT) return;
    int lane = threadIdx.x & 63;
    int r0 = row_ptr[node], r1 = row_ptr[node + 1];
    if (r0 >= r1) return;
    float m = -__builtin_inff();
    for (int k = r0 + lane; k < r1; k += 64) m = fmaxf(m, __int_as_float(pair[k].y));
#pragma unroll
    for (int o = 1; o < 64; o <<= 1) m = fmaxf(m, __shfl_xor(m, o));
    float s = 0.f;
    for (int k = r0 + lane; k < r1; k += 64) s += __expf(__int_as_float(pair[k].y) - m);
#pragma unroll
    for (int o = 1; o < 64; o <<= 1) s += __shfl_xor(s, o);
    float inv = (s > 0.f) ? 1.f / s : 0.f;
    for (int k = r0 + lane; k < r1; k += 64) {
        float wv = __expf(__int_as_float(pair[k].y) - m) * inv;
        pair[k].y = __float_as_int(wv);
    }
}

// ---------- aggregation, 4-edge MLP unroll: aggb[n][j] = (bf16) sum_k w[k]*feat[src[k]][j] ----------
template <typename FT>
__global__ __launch_bounds__(256) void agg_kernel(const int* __restrict__ row_ptr, const int2* __restrict__ pair,
                                                  const FT* __restrict__ feat, bf16* __restrict__ aggb) {
    int node = blockIdx.x * 4 + (threadIdx.x >> 6);
    if (node >= N_ENT) return;
    int lane = threadIdx.x & 63;
    int r0 = row_ptr[node], r1 = row_ptr[node + 1];
    float acc = 0.f;
    int k = r0;
    for (; k + 4 <= r1; k += 4) {
        int2 p0 = pair[k], p1 = pair[k + 1], p2 = pair[k + 2], p3 = pair[k + 3];
        float f0 = (float)feat[(size_t)p0.x * 64 + lane];
        float f1 = (float)feat[(size_t)p1.x * 64 + lane];
        float f2 = (float)feat[(size_t)p2.x * 64 + lane];
        float f3 = (float)feat[(size_t)p3.x * 64 + lane];
        acc += __int_as_float(p0.y) * f0; acc += __int_as_float(p1.y) * f1;
        acc += __int_as_float(p2.y) * f2; acc += __int_as_float(p3.y) * f3;
    }
    for (; k < r1; ++k) {
        int2 p = pair[k];
        acc += __int_as_float(p.y) * (float)feat[(size_t)p.x * 64 + lane];
    }
    aggb[(size_t)node * 64 + lane] = (bf16)acc;
}

// ---------- layer 1 ----------
__global__ __launch_bounds__(256) void transform1_kernel(const float* __restrict__ ent, const bf16* __restrict__ aggb,
                                                         const float* __restrict__ W0, bf16* __restrict__ h1b,
                                                         float* __restrict__ out) {
    __shared__ float Ws[64 * 65];
    int t = threadIdx.x;
    for (int idx = t; idx < 4096; idx += 256) { int d = idx >> 6, j = idx & 63; Ws[d * 65 + j] = W0[idx]; }
    __syncthreads();
    int node = blockIdx.x * 4 + (t >> 6);
    if (node >= N_ENT) return;
    int j = t & 63;
    float h0v = ent[(size_t)node * 64 + j];
    float x = h0v * (float)aggb[(size_t)node * 64 + j];
    float acc = 0.f;
#pragma unroll
    for (int d = 0; d < 64; ++d) acc += __shfl(x, d) * Ws[d * 65 + j];
    float h1v = acc > 0.f ? acc : 0.01f * acc;
    h1b[(size_t)node * 64 + j] = (bf16)h1v;
    float ss = h1v * h1v;
#pragma unroll
    for (int o = 1; o < 64; o <<= 1) ss += __shfl_xor(ss, o);
    float inv = 1.f / fmaxf(sqrtf(ss), 1e-12f);
    out[(size_t)node * OUT_STRIDE + j] = h0v;
    out[(size_t)node * OUT_STRIDE + 64 + j] = h1v * inv;
}

// ---------- layer 2 ----------
__global__ __launch_bounds__(256) void transform2_kernel(const bf16* __restrict__ h1b, const bf16* __restrict__ aggb,
                                                         const float* __restrict__ W1, float* __restrict__ out) {
    __shared__ float Ws[64 * 33];
    int t = threadIdx.x;
    for (int idx = t; idx < 2048; idx += 256) { int d = idx >> 5, j = idx & 31; Ws[d * 33 + j] = W1[idx]; }
    __syncthreads();
    int node = blockIdx.x * 4 + (t >> 6);
    if (node >= N_ENT) return;
    int j = t & 63;
    float x = (float)h1b[(size_t)node * 64 + j] * (float)aggb[(size_t)node * 64 + j];
    int base = j & 32, jj = j & 31;
    float acc = 0.f;
#pragma unroll
    for (int i = 0; i < 32; ++i) acc += __shfl(x, base + i) * Ws[(base + i) * 33 + jj];
    acc += __shfl_xor(acc, 32);
    float h2 = acc > 0.f ? acc : 0.01f * acc;
    float ss = h2 * h2;
#pragma unroll
    for (int o = 1; o < 32; o <<= 1) ss += __shfl_xor(ss, o);
    float inv = 1.f / fmaxf(sqrtf(ss), 1e-12f);
    if (j < 32) out[(size_t)node * OUT_STRIDE + 128 + jj] = h2 * inv;
}

extern "C" void kernel_launch(void* const* d_in, const int* in_sizes, int n_in,
                              void* d_out, int out_size, void* d_ws, size_t ws_size,
                              hipStream_t stream) {
    const float* ent = (const float*)d_in[0];
    const float* rel = (const float*)d_in[1];
    const float* W_R = (const float*)d_in[2];
    const float* W0  = (const float*)d_in[3];
    const float* W1  = (const float*)d_in[4];
    const int*   src = (const int*)d_in[5];
    const int*   dst = (const int*)d_in[6];
    const int*   ety = (const int*)d_in[7];
    float* out = (float*)d_out;

    char* ws = (char*)d_ws;
    size_t off = 0;
    auto take = [&](size_t bytes) -> char* {
        char* p = ws + off;
        off += (bytes + 255) & ~(size_t)255;
        return p;
    };
    // dead-after-dst_scatter pool (hosts h1b/aggb overlays):
    int*   bsrc  = (int*)take((size_t)E_PAD * 4);        // 6.40 MB
    int*   bdst  = (int*)take((size_t)E_PAD * 4);        // 6.40 MB
    float* att   = (float*)take((size_t)E_PAD * 4);      // 6.40 MB
    int*   cnt   = (int*)take((size_t)(N_ENT + 16) * 4); // cnt16 = cnt+N_ENT
    int*   cnt16 = cnt + N_ENT;
    int*   cur   = (int*)take((size_t)N_ENT * 4);
    int*   part  = (int*)take(NCHUNK * 4);
    int*   pbase = (int*)take(NCHUNK * 4);
    (void)take(5600000);                                  // overlay pad so aggb span fits
    // live-to-the-end:
    int2*  pair  = (int2*)take((size_t)N_EDGES * 8);     // 12.8 MB {src, att->w}
    int*   rowp  = (int*)take((size_t)(N_ENT + 1) * 4);
    int*   bptr16= (int*)take(68);
    int*   cur16 = (int*)take(64);
    size_t needed = off;                                  // ~39 MB
    // overlays: h1b over {bsrc,bdst} (12.80 MB need <= 12.80 MB span);
    //           aggb over {att..ovpad} (12.80 MB need <= ~12.8 MB span). Both pools dead after dst_scatter.
    bf16* h1b  = (bf16*)bsrc;
    bf16* aggb = (bf16*)att;

    if (needed > ws_size) {
        zero_out_kernel<<<512, 256, 0, stream>>>(out, out_size);
        return;
    }

    fill_kernel<<<512, 256, 0, stream>>>(cnt, 0, N_ENT + 16);
    fill_kernel<<<512, 256, 0, stream>>>(bdst, -1, E_PAD);   // pad-slot sentinel

    hist16_kernel<<<N_EDGES / 256, 256, 0, stream>>>(ety, cnt16);
    bucket_scan<<<1, 64, 0, stream>>>(cnt16, bptr16, cur16);
    bucket_scatter<<<N_EDGES / 256, 256, 0, stream>>>(src, dst, ety, cur16, bsrc, bdst, cnt);

    fused_att<<<dim3(64, N_REL), 256, 0, stream>>>(ent, W_R, rel, bsrc, bdst, bptr16, att);

    scan1<<<NCHUNK, 256, 0, stream>>>(cnt, part);
    scan2<<<1, 64, 0, stream>>>(part, pbase);
    scan3<<<NCHUNK, 256, 0, stream>>>(cnt, pbase, rowp, cur);
    dst_scatter<<<(E_PAD + 255) / 256, 256, 0, stream>>>(bdst, bsrc, att, cur, pair);

    softmax_kernel<<<N_ENT / 4, 256, 0, stream>>>(rowp, pair);
    agg_kernel<float><<<N_ENT / 4, 256, 0, stream>>>(rowp, pair, ent, aggb);
    transform1_kernel<<<N_ENT / 4, 256, 0, stream>>>(ent, aggb, W0, h1b, out);
    agg_kernel<bf16><<<N_ENT / 4, 256, 0, stream>>>(rowp, pair, h1b, aggb);
    transform2_kernel<<<N_ENT / 4, 256, 0, stream>>>(h1b, aggb, W1, out);
}

// Round 10
// 737.158 us; speedup vs baseline: 6.6117x; 1.1772x over previous
//
#include <hip/hip_runtime.h>
#include <hip/hip_bf16.h>
#include <math.h>

typedef __bf16 bf16;
typedef __bf16 bf16x8 __attribute__((ext_vector_type(8)));
typedef float f32x4 __attribute__((ext_vector_type(4)));

#define N_ENT   100000
#define N_REL   16
#define N_EDGES 1600000
#define E_PAD   (N_EDGES + 256)   // bucket records padded (<=16 pad slots per relation)
#define OUT_STRIDE 160
#define NCHUNK  98   // ceil(N_ENT/1024)

// ---------- fill an int region (grid-stride) ----------
__global__ __launch_bounds__(256) void fill_kernel(int* __restrict__ p, int v, int n) {
    int i = blockIdx.x * 256 + threadIdx.x;
    int stride = gridDim.x * 256;
    for (; i < n; i += stride) p[i] = v;
}

// ---------- ws-too-small tripwire ----------
__global__ __launch_bounds__(256) void zero_out_kernel(float* __restrict__ out, int n) {
    int i = blockIdx.x * 256 + threadIdx.x;
    int stride = gridDim.x * 256;
    for (; i < n; i += stride) out[i] = 0.f;
}

// ---------- ent (fp32) -> entb (bf16), 4 elems/thread ----------
__global__ __launch_bounds__(256) void ent2b_kernel(const float* __restrict__ ent, bf16* __restrict__ entb) {
    int i = (blockIdx.x * 256 + threadIdx.x) * 4;
    int stride = gridDim.x * 1024;
    for (; i < N_ENT * 64; i += stride) {
        float4 v = *(const float4*)(ent + i);
        entb[i]     = (bf16)v.x;
        entb[i + 1] = (bf16)v.y;
        entb[i + 2] = (bf16)v.z;
        entb[i + 3] = (bf16)v.w;
    }
}

// ---------- etype histogram (LDS-staged) ----------
__global__ __launch_bounds__(256) void hist16_kernel(const int* __restrict__ ety, int* __restrict__ cnt16) {
    __shared__ int h16[16];
    int t = threadIdx.x;
    if (t < 16) h16[t] = 0;
    __syncthreads();
    int e = blockIdx.x * 256 + t;
    if (e < N_EDGES) atomicAdd(&h16[ety[e]], 1);
    __syncthreads();
    if (t < 16 && h16[t] > 0) atomicAdd(&cnt16[t], h16[t]);
}

// padded bucket offsets (each bucket start multiple of 16)
__global__ void bucket_scan(const int* __restrict__ cnt16, int* __restrict__ bptr16, int* __restrict__ cur16) {
    if (threadIdx.x == 0) {
        int s = 0;
        for (int r = 0; r < N_REL; ++r) {
            bptr16[r] = s; cur16[r] = s;
            s += (cnt16[r] + 15) & ~15;
        }
        bptr16[N_REL] = s;
    }
}

// ballot-rank scatter into padded etype buckets; record = {src, dst, within-dst rank, 0}
// rank comes FREE from the dst-degree histogram atomic's return value.
__global__ __launch_bounds__(256) void bucket_scatter(const int* __restrict__ src, const int* __restrict__ dst,
                                                      const int* __restrict__ ety, int* __restrict__ cur16,
                                                      int4* __restrict__ bedge, int* __restrict__ cnt) {
    __shared__ int whist[4][16];
    __shared__ int wbase[4][16];
    __shared__ int bbase[16];
    int t = threadIdx.x, wave = t >> 6, lane = t & 63;
    int e = blockIdx.x * 256 + t;
    int b = -1, d = 0, nrank = 0;
    if (e < N_EDGES) {
        b = ety[e];
        d = dst[e];
        nrank = atomicAdd(&cnt[d], 1);
    }
    unsigned long long ltmask = (1ull << lane) - 1ull;
    int brk = 0;
#pragma unroll
    for (int r = 0; r < 16; ++r) {
        unsigned long long mk = __ballot(b == r);
        if (b == r) brk = __popcll(mk & ltmask);
        if (lane == r) whist[wave][r] = __popcll(mk);
    }
    __syncthreads();
    if (t < 16) {
        int s0 = whist[0][t], s1 = whist[1][t], s2 = whist[2][t], s3 = whist[3][t];
        bbase[t] = atomicAdd(&cur16[t], s0 + s1 + s2 + s3);
        wbase[0][t] = 0; wbase[1][t] = s0; wbase[2][t] = s0 + s1; wbase[3][t] = s0 + s1 + s2;
    }
    __syncthreads();
    if (b >= 0) {
        int pos = bbase[b] + wbase[wave][b] + brk;
        bedge[pos] = make_int4(src[e], d, nrank, 0);
    }
}

// ---------- dst-CSR scans ----------
__global__ __launch_bounds__(256) void scan1(const int* __restrict__ cnt, int* __restrict__ part) {
    __shared__ int sh[256];
    int bIdx = blockIdx.x, t = threadIdx.x;
    int i0 = bIdx * 1024 + t * 4;
    int s = 0;
#pragma unroll
    for (int u = 0; u < 4; ++u) { int i = i0 + u; if (i < N_ENT) s += cnt[i]; }
    sh[t] = s; __syncthreads();
    for (int o = 128; o > 0; o >>= 1) { if (t < o) sh[t] += sh[t + o]; __syncthreads(); }
    if (t == 0) part[bIdx] = sh[0];
}

__global__ void scan2(const int* __restrict__ part, int* __restrict__ pbase) {
    if (threadIdx.x == 0) {
        int s = 0;
        for (int i = 0; i < NCHUNK; ++i) { pbase[i] = s; s += part[i]; }
    }
}

__global__ __launch_bounds__(256) void scan3(const int* __restrict__ cnt, const int* __restrict__ pbase,
                                             int* __restrict__ row_ptr) {
    __shared__ int sh[256];
    int bIdx = blockIdx.x, t = threadIdx.x;
    int i0 = bIdx * 1024 + t * 4;
    int c[4]; int s = 0;
#pragma unroll
    for (int u = 0; u < 4; ++u) { c[u] = (i0 + u < N_ENT) ? cnt[i0 + u] : 0; s += c[u]; }
    sh[t] = s; __syncthreads();
    for (int o = 1; o < 256; o <<= 1) {
        int add = (t >= o) ? sh[t - o] : 0;
        __syncthreads();
        sh[t] += add;
        __syncthreads();
    }
    int run = pbase[bIdx] + sh[t] - s;
#pragma unroll
    for (int u = 0; u < 4; ++u) {
        if (i0 + u < N_ENT) { row_ptr[i0 + u] = run; run += c[u]; }
    }
    if (bIdx == 0 && t == 0) row_ptr[N_ENT] = N_EDGES;
}

// ---------- fused per-edge MFMA attention, writes pair[rowp[d]+rank] directly ----------
// Per 16-edge group g: T = ENTB[src] @ W_r, H = ENTB[dst] @ W_r (16x64 each),
// att = sum_n T*tanh(H+rel_r). A-frag: rows = edges (gathered bf16x8).
// B-frag: B[k=q*8+j][n=lane&15] from LDS WT[n][k]. C/D: col=n, row=q*4+i=edge (m89).
__global__ __launch_bounds__(256) void fused_att(const bf16* __restrict__ entb, const float* __restrict__ W_R,
                                                 const float* __restrict__ rel, const int4* __restrict__ bedge,
                                                 const int* __restrict__ bptr16, const int* __restrict__ rowp,
                                                 int2* __restrict__ pair) {
    __shared__ bf16 WT[64 * 72];     // WT[n][k] = W_r[k][n]
    __shared__ float relS[64];
    const int r = blockIdx.y;
    const int t = threadIdx.x;
    const float* Wr = W_R + (size_t)r * 4096;
    for (int idx = t; idx < 4096; idx += 256) {
        int k = idx >> 6, n = idx & 63;
        WT[n * 72 + k] = (bf16)Wr[idx];
    }
    if (t < 64) relS[t] = rel[r * 64 + t];
    __syncthreads();

    const int lane = t & 63, m = lane & 15, q = lane >> 4;
    bf16x8 bb[4][2];
#pragma unroll
    for (int nt = 0; nt < 4; ++nt)
#pragma unroll
        for (int ks = 0; ks < 2; ++ks)
            bb[nt][ks] = *(const bf16x8*)&WT[(nt * 16 + m) * 72 + ks * 32 + q * 8];

    int g0 = bptr16[r] >> 4, g1 = bptr16[r + 1] >> 4;
    int wv = blockIdx.x * 4 + (t >> 6);
    int nw = gridDim.x * 4;
    for (int g = g0 + wv; g < g1; g += nw) {
        int4 be = bedge[g * 16 + m];
        int sidx = be.x < 0 ? 0 : be.x;      // pad slots clamped for the gather
        int didx = be.y < 0 ? 0 : be.y;
        const bf16* sp = entb + (size_t)sidx * 64;
        const bf16* dp = entb + (size_t)didx * 64;
        bf16x8 as0 = *(const bf16x8*)(sp + q * 8);
        bf16x8 as1 = *(const bf16x8*)(sp + 32 + q * 8);
        bf16x8 ad0 = *(const bf16x8*)(dp + q * 8);
        bf16x8 ad1 = *(const bf16x8*)(dp + 32 + q * 8);
        float part0 = 0.f, part1 = 0.f, part2 = 0.f, part3 = 0.f;
#pragma unroll
        for (int nt = 0; nt < 4; ++nt) {
            f32x4 tacc = {0.f, 0.f, 0.f, 0.f};
            tacc = __builtin_amdgcn_mfma_f32_16x16x32_bf16(as0, bb[nt][0], tacc, 0, 0, 0);
            tacc = __builtin_amdgcn_mfma_f32_16x16x32_bf16(as1, bb[nt][1], tacc, 0, 0, 0);
            f32x4 hacc = {0.f, 0.f, 0.f, 0.f};
            hacc = __builtin_amdgcn_mfma_f32_16x16x32_bf16(ad0, bb[nt][0], hacc, 0, 0, 0);
            hacc = __builtin_amdgcn_mfma_f32_16x16x32_bf16(ad1, bb[nt][1], hacc, 0, 0, 0);
            float rl = relS[nt * 16 + m];
#pragma unroll
            for (int i = 0; i < 4; ++i) {
                float z = hacc[i] + rl;
                float ez = __expf(2.f * z);                 // tanh(z) = 1 - 2/(e^{2z}+1)
                float th = 1.f - 2.f / (ez + 1.f);
                float tv = tacc[i] * th;
                if (i == 0) part0 += tv; else if (i == 1) part1 += tv;
                else if (i == 2) part2 += tv; else part3 += tv;
            }
        }
#pragma unroll
        for (int o = 1; o < 16; o <<= 1) {    // reduce over dim-lanes; xor<16 stays in edge group
            part0 += __shfl_xor(part0, o);
            part1 += __shfl_xor(part1, o);
            part2 += __shfl_xor(part2, o);
            part3 += __shfl_xor(part3, o);
        }
        if (m == 0) {
            float v[4] = {part0, part1, part2, part3};
#pragma unroll
            for (int i = 0; i < 4; ++i) {
                int4 w = bedge[g * 16 + q * 4 + i];          // L1-hot reread
                if (w.y >= 0) {
                    int slot = rowp[w.y] + w.z;              // unique CSR slot, no atomic
                    pair[slot] = make_int2(w.x, __float_as_int(v[i]));
                }
            }
        }
    }
}

// ---------- per-dst softmax, coalesced; overwrites pair.y with w ----------
__global__ __launch_bounds__(256) void softmax_kernel(const int* __restrict__ row_ptr, int2* __restrict__ pair) {
    int node = blockIdx.x * 4 + (threadIdx.x >> 6);
    if (node >= N_ENT) return;
    int lane = threadIdx.x & 63;
    int r0 = row_ptr[node], r1 = row_ptr[node + 1];
    if (r0 >= r1) return;
    float m = -__builtin_inff();
    for (int k = r0 + lane; k < r1; k += 64) m = fmaxf(m, __int_as_float(pair[k].y));
#pragma unroll
    for (int o = 1; o < 64; o <<= 1) m = fmaxf(m, __shfl_xor(m, o));
    float s = 0.f;
    for (int k = r0 + lane; k < r1; k += 64) s += __expf(__int_as_float(pair[k].y) - m);
#pragma unroll
    for (int o = 1; o < 64; o <<= 1) s += __shfl_xor(s, o);
    float inv = (s > 0.f) ? 1.f / s : 0.f;
    for (int k = r0 + lane; k < r1; k += 64) {
        float wv = __expf(__int_as_float(pair[k].y) - m) * inv;
        pair[k].y = __float_as_int(wv);
    }
}

// ---------- aggregation, 4-edge MLP unroll ----------
__global__ __launch_bounds__(256) void agg_kernel(const int* __restrict__ row_ptr, const int2* __restrict__ pair,
                                                  const bf16* __restrict__ feat, bf16* __restrict__ aggb) {
    int node = blockIdx.x * 4 + (threadIdx.x >> 6);
    if (node >= N_ENT) return;
    int lane = threadIdx.x & 63;
    int r0 = row_ptr[node], r1 = row_ptr[node + 1];
    float acc = 0.f;
    int k = r0;
    for (; k + 4 <= r1; k += 4) {
        int2 p0 = pair[k], p1 = pair[k + 1], p2 = pair[k + 2], p3 = pair[k + 3];
        float f0 = (float)feat[(size_t)p0.x * 64 + lane];
        float f1 = (float)feat[(size_t)p1.x * 64 + lane];
        float f2 = (float)feat[(size_t)p2.x * 64 + lane];
        float f3 = (float)feat[(size_t)p3.x * 64 + lane];
        acc += __int_as_float(p0.y) * f0; acc += __int_as_float(p1.y) * f1;
        acc += __int_as_float(p2.y) * f2; acc += __int_as_float(p3.y) * f3;
    }
    for (; k < r1; ++k) {
        int2 p = pair[k];
        acc += __int_as_float(p.y) * (float)feat[(size_t)p.x * 64 + lane];
    }
    aggb[(size_t)node * 64 + lane] = (bf16)acc;
}

// ---------- layer 1 ----------
__global__ __launch_bounds__(256) void transform1_kernel(const float* __restrict__ ent, const bf16* __restrict__ aggb,
                                                         const float* __restrict__ W0, bf16* __restrict__ h1b,
                                                         float* __restrict__ out) {
    __shared__ float Ws[64 * 65];
    int t = threadIdx.x;
    for (int idx = t; idx < 4096; idx += 256) { int d = idx >> 6, j = idx & 63; Ws[d * 65 + j] = W0[idx]; }
    __syncthreads();
    int node = blockIdx.x * 4 + (t >> 6);
    if (node >= N_ENT) return;
    int j = t & 63;
    float h0v = ent[(size_t)node * 64 + j];
    float x = h0v * (float)aggb[(size_t)node * 64 + j];
    float acc = 0.f;
#pragma unroll
    for (int d = 0; d < 64; ++d) acc += __shfl(x, d) * Ws[d * 65 + j];
    float h1v = acc > 0.f ? acc : 0.01f * acc;
    h1b[(size_t)node * 64 + j] = (bf16)h1v;
    float ss = h1v * h1v;
#pragma unroll
    for (int o = 1; o < 64; o <<= 1) ss += __shfl_xor(ss, o);
    float inv = 1.f / fmaxf(sqrtf(ss), 1e-12f);
    out[(size_t)node * OUT_STRIDE + j] = h0v;
    out[(size_t)node * OUT_STRIDE + 64 + j] = h1v * inv;
}

// ---------- layer 2 ----------
__global__ __launch_bounds__(256) void transform2_kernel(const bf16* __restrict__ h1b, const bf16* __restrict__ aggb,
                                                         const float* __restrict__ W1, float* __restrict__ out) {
    __shared__ float Ws[64 * 33];
    int t = threadIdx.x;
    for (int idx = t; idx < 2048; idx += 256) { int d = idx >> 5, j = idx & 31; Ws[d * 33 + j] = W1[idx]; }
    __syncthreads();
    int node = blockIdx.x * 4 + (t >> 6);
    if (node >= N_ENT) return;
    int j = t & 63;
    float x = (float)h1b[(size_t)node * 64 + j] * (float)aggb[(size_t)node * 64 + j];
    int base = j & 32, jj = j & 31;
    float acc = 0.f;
#pragma unroll
    for (int i = 0; i < 32; ++i) acc += __shfl(x, base + i) * Ws[(base + i) * 33 + jj];
    acc += __shfl_xor(acc, 32);
    float h2 = acc > 0.f ? acc : 0.01f * acc;
    float ss = h2 * h2;
#pragma unroll
    for (int o = 1; o < 32; o <<= 1) ss += __shfl_xor(ss, o);
    float inv = 1.f / fmaxf(sqrtf(ss), 1e-12f);
    if (j < 32) out[(size_t)node * OUT_STRIDE + 128 + jj] = h2 * inv;
}

extern "C" void kernel_launch(void* const* d_in, const int* in_sizes, int n_in,
                              void* d_out, int out_size, void* d_ws, size_t ws_size,
                              hipStream_t stream) {
    const float* ent = (const float*)d_in[0];
    const float* rel = (const float*)d_in[1];
    const float* W_R = (const float*)d_in[2];
    const float* W0  = (const float*)d_in[3];
    const float* W1  = (const float*)d_in[4];
    const int*   src = (const int*)d_in[5];
    const int*   dst = (const int*)d_in[6];
    const int*   ety = (const int*)d_in[7];
    float* out = (float*)d_out;

    char* ws = (char*)d_ws;
    size_t off = 0;
    auto take = [&](size_t bytes) -> char* {
        char* p = ws + off;
        off += (bytes + 255) & ~(size_t)255;
        return p;
    };
    int4*  bedge = (int4*)take((size_t)E_PAD * 16);       // 25.6 MB {src,dst,rank,0}; dead after fused_att
    bf16*  entb  = (bf16*)take((size_t)N_ENT * 64 * 2);   // 12.8 MB bf16 entity rows
    int2*  pair  = (int2*)take((size_t)N_EDGES * 8);      // 12.8 MB {src, att->w} in CSR order
    int*   cnt   = (int*)take((size_t)(N_ENT + 16) * 4);  // cnt16 = cnt+N_ENT
    int*   cnt16 = cnt + N_ENT;
    int*   rowp  = (int*)take((size_t)(N_ENT + 1) * 4);
    int*   part  = (int*)take(NCHUNK * 4);
    int*   pbase = (int*)take(NCHUNK * 4);
    int*   bptr16= (int*)take(68);
    int*   cur16 = (int*)take(64);
    size_t needed = off;                                   // ~52.2 MB
    // overlays: h1b (12.8) + aggb (12.8) over bedge (25.6, dead after fused_att)
    bf16* h1b  = (bf16*)bedge;
    bf16* aggb = (bf16*)bedge + (size_t)N_ENT * 64;

    if (needed > ws_size) {
        zero_out_kernel<<<512, 256, 0, stream>>>(out, out_size);
        return;
    }

    fill_kernel<<<512, 256, 0, stream>>>(cnt, 0, N_ENT + 16);
    fill_kernel<<<2048, 256, 0, stream>>>((int*)bedge, -1, E_PAD * 4);  // pad sentinel (dst=-1)
    ent2b_kernel<<<2048, 256, 0, stream>>>(ent, entb);

    hist16_kernel<<<N_EDGES / 256, 256, 0, stream>>>(ety, cnt16);
    bucket_scan<<<1, 64, 0, stream>>>(cnt16, bptr16, cur16);
    bucket_scatter<<<N_EDGES / 256, 256, 0, stream>>>(src, dst, ety, cur16, bedge, cnt);

    scan1<<<NCHUNK, 256, 0, stream>>>(cnt, part);
    scan2<<<1, 64, 0, stream>>>(part, pbase);
    scan3<<<NCHUNK, 256, 0, stream>>>(cnt, pbase, rowp);

    fused_att<<<dim3(128, N_REL), 256, 0, stream>>>(entb, W_R, rel, bedge, bptr16, rowp, pair);

    softmax_kernel<<<N_ENT / 4, 256, 0, stream>>>(rowp, pair);
    agg_kernel<<<N_ENT / 4, 256, 0, stream>>>(rowp, pair, entb, aggb);
    transform1_kernel<<<N_ENT / 4, 256, 0, stream>>>(ent, aggb, W0, h1b, out);
    agg_kernel<<<N_ENT / 4, 256, 0, stream>>>(rowp, pair, h1b, aggb);
    transform2_kernel<<<N_ENT / 4, 256, 0, stream>>>(h1b, aggb, W1, out);
}

// Round 11
// 683.487 us; speedup vs baseline: 7.1309x; 1.0785x over previous
//
#include <hip/hip_runtime.h>
#include <hip/hip_bf16.h>
#include <math.h>

typedef __bf16 bf16;
typedef __bf16 bf16x8 __attribute__((ext_vector_type(8)));
typedef float f32x4 __attribute__((ext_vector_type(4)));

#define N_ENT   100000
#define N_REL   16
#define N_EDGES 1600000
#define E_PAD   (N_EDGES + 256)   // bucket records padded (<=16 pad slots per relation)
#define OUT_STRIDE 160
#define NCHUNK  98   // ceil(N_ENT/1024)

// ---------- fill an int region (grid-stride) ----------
__global__ __launch_bounds__(256) void fill_kernel(int* __restrict__ p, int v, int n) {
    int i = blockIdx.x * 256 + threadIdx.x;
    int stride = gridDim.x * 256;
    for (; i < n; i += stride) p[i] = v;
}

// ---------- ws-too-small tripwire ----------
__global__ __launch_bounds__(256) void zero_out_kernel(float* __restrict__ out, int n) {
    int i = blockIdx.x * 256 + threadIdx.x;
    int stride = gridDim.x * 256;
    for (; i < n; i += stride) out[i] = 0.f;
}

// ---------- ent (fp32) -> entb (bf16) ----------
__global__ __launch_bounds__(256) void ent2b_kernel(const float* __restrict__ ent, bf16* __restrict__ entb) {
    int i = (blockIdx.x * 256 + threadIdx.x) * 4;
    int stride = gridDim.x * 1024;
    for (; i < N_ENT * 64; i += stride) {
        float4 v = *(const float4*)(ent + i);
        entb[i]     = (bf16)v.x;
        entb[i + 1] = (bf16)v.y;
        entb[i + 2] = (bf16)v.z;
        entb[i + 3] = (bf16)v.w;
    }
}

// ---------- etype histogram (LDS-staged) ----------
__global__ __launch_bounds__(256) void hist16_kernel(const int* __restrict__ ety, int* __restrict__ cnt16) {
    __shared__ int h16[16];
    int t = threadIdx.x;
    if (t < 16) h16[t] = 0;
    __syncthreads();
    int e = blockIdx.x * 256 + t;
    if (e < N_EDGES) atomicAdd(&h16[ety[e]], 1);
    __syncthreads();
    if (t < 16 && h16[t] > 0) atomicAdd(&cnt16[t], h16[t]);
}

// padded bucket offsets (each bucket start multiple of 16)
__global__ void bucket_scan(const int* __restrict__ cnt16, int* __restrict__ bptr16, int* __restrict__ cur16) {
    if (threadIdx.x == 0) {
        int s = 0;
        for (int r = 0; r < N_REL; ++r) {
            bptr16[r] = s; cur16[r] = s;
            s += (cnt16[r] + 15) & ~15;
        }
        bptr16[N_REL] = s;
    }
}

// ballot-rank scatter into padded etype buckets; record = {src, dst, within-dst rank, 0}
__global__ __launch_bounds__(256) void bucket_scatter(const int* __restrict__ src, const int* __restrict__ dst,
                                                      const int* __restrict__ ety, int* __restrict__ cur16,
                                                      int4* __restrict__ bedge, int* __restrict__ cnt) {
    __shared__ int whist[4][16];
    __shared__ int wbase[4][16];
    __shared__ int bbase[16];
    int t = threadIdx.x, wave = t >> 6, lane = t & 63;
    int e = blockIdx.x * 256 + t;
    int b = -1, d = 0, nrank = 0;
    if (e < N_EDGES) {
        b = ety[e];
        d = dst[e];
        nrank = atomicAdd(&cnt[d], 1);
    }
    unsigned long long ltmask = (1ull << lane) - 1ull;
    int brk = 0;
#pragma unroll
    for (int r = 0; r < 16; ++r) {
        unsigned long long mk = __ballot(b == r);
        if (b == r) brk = __popcll(mk & ltmask);
        if (lane == r) whist[wave][r] = __popcll(mk);
    }
    __syncthreads();
    if (t < 16) {
        int s0 = whist[0][t], s1 = whist[1][t], s2 = whist[2][t], s3 = whist[3][t];
        bbase[t] = atomicAdd(&cur16[t], s0 + s1 + s2 + s3);
        wbase[0][t] = 0; wbase[1][t] = s0; wbase[2][t] = s0 + s1; wbase[3][t] = s0 + s1 + s2;
    }
    __syncthreads();
    if (b >= 0) {
        int pos = bbase[b] + wbase[wave][b] + brk;
        bedge[pos] = make_int4(src[e], d, nrank, 0);
    }
}

// ---------- dst-CSR scans ----------
__global__ __launch_bounds__(256) void scan1(const int* __restrict__ cnt, int* __restrict__ part) {
    __shared__ int sh[256];
    int bIdx = blockIdx.x, t = threadIdx.x;
    int i0 = bIdx * 1024 + t * 4;
    int s = 0;
#pragma unroll
    for (int u = 0; u < 4; ++u) { int i = i0 + u; if (i < N_ENT) s += cnt[i]; }
    sh[t] = s; __syncthreads();
    for (int o = 128; o > 0; o >>= 1) { if (t < o) sh[t] += sh[t + o]; __syncthreads(); }
    if (t == 0) part[bIdx] = sh[0];
}

__global__ void scan2(const int* __restrict__ part, int* __restrict__ pbase) {
    if (threadIdx.x == 0) {
        int s = 0;
        for (int i = 0; i < NCHUNK; ++i) { pbase[i] = s; s += part[i]; }
    }
}

__global__ __launch_bounds__(256) void scan3(const int* __restrict__ cnt, const int* __restrict__ pbase,
                                             int* __restrict__ row_ptr) {
    __shared__ int sh[256];
    int bIdx = blockIdx.x, t = threadIdx.x;
    int i0 = bIdx * 1024 + t * 4;
    int c[4]; int s = 0;
#pragma unroll
    for (int u = 0; u < 4; ++u) { c[u] = (i0 + u < N_ENT) ? cnt[i0 + u] : 0; s += c[u]; }
    sh[t] = s; __syncthreads();
    for (int o = 1; o < 256; o <<= 1) {
        int add = (t >= o) ? sh[t - o] : 0;
        __syncthreads();
        sh[t] += add;
        __syncthreads();
    }
    int run = pbase[bIdx] + sh[t] - s;
#pragma unroll
    for (int u = 0; u < 4; ++u) {
        if (i0 + u < N_ENT) { row_ptr[i0 + u] = run; run += c[u]; }
    }
    if (bIdx == 0 && t == 0) row_ptr[N_ENT] = N_EDGES;
}

// ---------- fused per-edge MFMA attention, writes pair[rowp[d]+rank] directly ----------
__global__ __launch_bounds__(256) void fused_att(const bf16* __restrict__ entb, const float* __restrict__ W_R,
                                                 const float* __restrict__ rel, const int4* __restrict__ bedge,
                                                 const int* __restrict__ bptr16, const int* __restrict__ rowp,
                                                 int2* __restrict__ pair) {
    __shared__ bf16 WT[64 * 72];     // WT[n][k] = W_r[k][n]
    __shared__ float relS[64];
    const int r = blockIdx.y;
    const int t = threadIdx.x;
    const float* Wr = W_R + (size_t)r * 4096;
    for (int idx = t; idx < 4096; idx += 256) {
        int k = idx >> 6, n = idx & 63;
        WT[n * 72 + k] = (bf16)Wr[idx];
    }
    if (t < 64) relS[t] = rel[r * 64 + t];
    __syncthreads();

    const int lane = t & 63, m = lane & 15, q = lane >> 4;
    bf16x8 bb[4][2];
#pragma unroll
    for (int nt = 0; nt < 4; ++nt)
#pragma unroll
        for (int ks = 0; ks < 2; ++ks)
            bb[nt][ks] = *(const bf16x8*)&WT[(nt * 16 + m) * 72 + ks * 32 + q * 8];

    int g0 = bptr16[r] >> 4, g1 = bptr16[r + 1] >> 4;
    int wv = blockIdx.x * 4 + (t >> 6);
    int nw = gridDim.x * 4;
    for (int g = g0 + wv; g < g1; g += nw) {
        int4 be = bedge[g * 16 + m];
        int sidx = be.x < 0 ? 0 : be.x;      // pad slots clamped for the gather
        int didx = be.y < 0 ? 0 : be.y;
        const bf16* sp = entb + (size_t)sidx * 64;
        const bf16* dp = entb + (size_t)didx * 64;
        bf16x8 as0 = *(const bf16x8*)(sp + q * 8);
        bf16x8 as1 = *(const bf16x8*)(sp + 32 + q * 8);
        bf16x8 ad0 = *(const bf16x8*)(dp + q * 8);
        bf16x8 ad1 = *(const bf16x8*)(dp + 32 + q * 8);
        float part0 = 0.f, part1 = 0.f, part2 = 0.f, part3 = 0.f;
#pragma unroll
        for (int nt = 0; nt < 4; ++nt) {
            f32x4 tacc = {0.f, 0.f, 0.f, 0.f};
            tacc = __builtin_amdgcn_mfma_f32_16x16x32_bf16(as0, bb[nt][0], tacc, 0, 0, 0);
            tacc = __builtin_amdgcn_mfma_f32_16x16x32_bf16(as1, bb[nt][1], tacc, 0, 0, 0);
            f32x4 hacc = {0.f, 0.f, 0.f, 0.f};
            hacc = __builtin_amdgcn_mfma_f32_16x16x32_bf16(ad0, bb[nt][0], hacc, 0, 0, 0);
            hacc = __builtin_amdgcn_mfma_f32_16x16x32_bf16(ad1, bb[nt][1], hacc, 0, 0, 0);
            float rl = relS[nt * 16 + m];
#pragma unroll
            for (int i = 0; i < 4; ++i) {
                float z = hacc[i] + rl;
                float ez = __expf(2.f * z);                 // tanh(z) = 1 - 2/(e^{2z}+1)
                float th = 1.f - 2.f / (ez + 1.f);
                float tv = tacc[i] * th;
                if (i == 0) part0 += tv; else if (i == 1) part1 += tv;
                else if (i == 2) part2 += tv; else part3 += tv;
            }
        }
#pragma unroll
        for (int o = 1; o < 16; o <<= 1) {    // reduce over dim-lanes; xor<16 stays in edge group
            part0 += __shfl_xor(part0, o);
            part1 += __shfl_xor(part1, o);
            part2 += __shfl_xor(part2, o);
            part3 += __shfl_xor(part3, o);
        }
        if (m == 0) {
            float v[4] = {part0, part1, part2, part3};
#pragma unroll
            for (int i = 0; i < 4; ++i) {
                int4 w = bedge[g * 16 + q * 4 + i];          // L1-hot reread
                if (w.y >= 0) {
                    int slot = rowp[w.y] + w.z;              // unique CSR slot, no atomic
                    pair[slot] = make_int2(w.x, __float_as_int(v[i]));
                }
            }
        }
    }
}

// ---------- fused layer 1: softmax + agg(entb) + transform1 (one wave per node) ----------
// pair.y holds ATT on entry; overwritten with w (for layer 2) AFTER the gather pass.
__global__ __launch_bounds__(256) void fused_layer1(const float* __restrict__ ent, const bf16* __restrict__ entb,
                                                    const float* __restrict__ W0, const int* __restrict__ rowp,
                                                    int2* __restrict__ pair, bf16* __restrict__ h1b,
                                                    float* __restrict__ out) {
    __shared__ float Ws[64 * 65];
    int t = threadIdx.x;
    for (int idx = t; idx < 4096; idx += 256) { int d = idx >> 6, j = idx & 63; Ws[d * 65 + j] = W0[idx]; }
    __syncthreads();
    int node = blockIdx.x * 4 + (t >> 6);
    if (node >= N_ENT) return;
    int j = t & 63;
    int r0 = rowp[node], r1 = rowp[node + 1];
    float acc = 0.f;
    if (r0 < r1) {
        float m = -__builtin_inff();
        for (int k = r0 + j; k < r1; k += 64) m = fmaxf(m, __int_as_float(pair[k].y));
#pragma unroll
        for (int o = 1; o < 64; o <<= 1) m = fmaxf(m, __shfl_xor(m, o));
        float s = 0.f;
        for (int k = r0 + j; k < r1; k += 64) s += __expf(__int_as_float(pair[k].y) - m);
#pragma unroll
        for (int o = 1; o < 64; o <<= 1) s += __shfl_xor(s, o);
        float inv = (s > 0.f) ? 1.f / s : 0.f;
        // gather pass: w computed inline from att (pair.y still att here)
        int k = r0;
        for (; k + 4 <= r1; k += 4) {
            int2 p0 = pair[k], p1 = pair[k + 1], p2 = pair[k + 2], p3 = pair[k + 3];
            float w0 = __expf(__int_as_float(p0.y) - m) * inv;
            float w1 = __expf(__int_as_float(p1.y) - m) * inv;
            float w2 = __expf(__int_as_float(p2.y) - m) * inv;
            float w3 = __expf(__int_as_float(p3.y) - m) * inv;
            float f0 = (float)entb[(size_t)p0.x * 64 + j];
            float f1 = (float)entb[(size_t)p1.x * 64 + j];
            float f2 = (float)entb[(size_t)p2.x * 64 + j];
            float f3 = (float)entb[(size_t)p3.x * 64 + j];
            acc += w0 * f0; acc += w1 * f1; acc += w2 * f2; acc += w3 * f3;
        }
        for (; k < r1; ++k) {
            int2 p = pair[k];
            acc += __expf(__int_as_float(p.y) - m) * inv * (float)entb[(size_t)p.x * 64 + j];
        }
        // write-back w for layer 2 (after gather: no store->load hazard)
        for (int k2 = r0 + j; k2 < r1; k2 += 64) {
            float wv = __expf(__int_as_float(pair[k2].y) - m) * inv;
            pair[k2].y = __float_as_int(wv);
        }
    }
    // transform1: h1 = lrelu((h0 * agg) @ W0); agg in fp32 registers
    float h0v = ent[(size_t)node * 64 + j];
    float x = h0v * acc;
    float a2 = 0.f;
#pragma unroll
    for (int d = 0; d < 64; ++d) a2 += __shfl(x, d) * Ws[d * 65 + j];
    float h1v = a2 > 0.f ? a2 : 0.01f * a2;
    h1b[(size_t)node * 64 + j] = (bf16)h1v;
    float ss = h1v * h1v;
#pragma unroll
    for (int o = 1; o < 64; o <<= 1) ss += __shfl_xor(ss, o);
    float inv2 = 1.f / fmaxf(sqrtf(ss), 1e-12f);
    out[(size_t)node * OUT_STRIDE + j] = h0v;
    out[(size_t)node * OUT_STRIDE + 64 + j] = h1v * inv2;
}

// ---------- fused layer 2: agg(h1b, w=pair.y) + transform2 ----------
__global__ __launch_bounds__(256) void fused_layer2(const bf16* __restrict__ h1b, const float* __restrict__ W1,
                                                    const int* __restrict__ rowp, const int2* __restrict__ pair,
                                                    float* __restrict__ out) {
    __shared__ float Ws[64 * 33];
    int t = threadIdx.x;
    for (int idx = t; idx < 2048; idx += 256) { int d = idx >> 5, j = idx & 31; Ws[d * 33 + j] = W1[idx]; }
    __syncthreads();
    int node = blockIdx.x * 4 + (t >> 6);
    if (node >= N_ENT) return;
    int j = t & 63;
    int r0 = rowp[node], r1 = rowp[node + 1];
    float acc = 0.f;
    int k = r0;
    for (; k + 4 <= r1; k += 4) {
        int2 p0 = pair[k], p1 = pair[k + 1], p2 = pair[k + 2], p3 = pair[k + 3];
        float f0 = (float)h1b[(size_t)p0.x * 64 + j];
        float f1 = (float)h1b[(size_t)p1.x * 64 + j];
        float f2 = (float)h1b[(size_t)p2.x * 64 + j];
        float f3 = (float)h1b[(size_t)p3.x * 64 + j];
        acc += __int_as_float(p0.y) * f0; acc += __int_as_float(p1.y) * f1;
        acc += __int_as_float(p2.y) * f2; acc += __int_as_float(p3.y) * f3;
    }
    for (; k < r1; ++k) {
        int2 p = pair[k];
        acc += __int_as_float(p.y) * (float)h1b[(size_t)p.x * 64 + j];
    }
    float x = (float)h1b[(size_t)node * 64 + j] * acc;
    int base = j & 32, jj = j & 31;
    float a2 = 0.f;
#pragma unroll
    for (int i = 0; i < 32; ++i) a2 += __shfl(x, base + i) * Ws[(base + i) * 33 + jj];
    a2 += __shfl_xor(a2, 32);
    float h2 = a2 > 0.f ? a2 : 0.01f * a2;
    float ss = h2 * h2;
#pragma unroll
    for (int o = 1; o < 32; o <<= 1) ss += __shfl_xor(ss, o);
    float inv = 1.f / fmaxf(sqrtf(ss), 1e-12f);
    if (j < 32) out[(size_t)node * OUT_STRIDE + 128 + jj] = h2 * inv;
}

extern "C" void kernel_launch(void* const* d_in, const int* in_sizes, int n_in,
                              void* d_out, int out_size, void* d_ws, size_t ws_size,
                              hipStream_t stream) {
    const float* ent = (const float*)d_in[0];
    const float* rel = (const float*)d_in[1];
    const float* W_R = (const float*)d_in[2];
    const float* W0  = (const float*)d_in[3];
    const float* W1  = (const float*)d_in[4];
    const int*   src = (const int*)d_in[5];
    const int*   dst = (const int*)d_in[6];
    const int*   ety = (const int*)d_in[7];
    float* out = (float*)d_out;

    char* ws = (char*)d_ws;
    size_t off = 0;
    auto take = [&](size_t bytes) -> char* {
        char* p = ws + off;
        off += (bytes + 255) & ~(size_t)255;
        return p;
    };
    int4*  bedge = (int4*)take((size_t)E_PAD * 16);       // 25.6 MB {src,dst,rank,0}; dead after fused_att
    bf16*  entb  = (bf16*)take((size_t)N_ENT * 64 * 2);   // 12.8 MB bf16 entity rows
    int2*  pair  = (int2*)take((size_t)N_EDGES * 8);      // 12.8 MB {src, att->w} in CSR order
    int*   cnt   = (int*)take((size_t)(N_ENT + 16) * 4);  // cnt16 = cnt+N_ENT
    int*   cnt16 = cnt + N_ENT;
    int*   rowp  = (int*)take((size_t)(N_ENT + 1) * 4);
    int*   part  = (int*)take(NCHUNK * 4);
    int*   pbase = (int*)take(NCHUNK * 4);
    int*   bptr16= (int*)take(68);
    int*   cur16 = (int*)take(64);
    size_t needed = off;                                   // ~52.2 MB
    // overlay: h1b (12.8) over bedge (25.6, dead after fused_att)
    bf16* h1b = (bf16*)bedge;

    if (needed > ws_size) {
        zero_out_kernel<<<512, 256, 0, stream>>>(out, out_size);
        return;
    }

    fill_kernel<<<512, 256, 0, stream>>>(cnt, 0, N_ENT + 16);
    fill_kernel<<<2048, 256, 0, stream>>>((int*)bedge, -1, E_PAD * 4);  // pad sentinel (dst=-1)
    ent2b_kernel<<<2048, 256, 0, stream>>>(ent, entb);

    hist16_kernel<<<N_EDGES / 256, 256, 0, stream>>>(ety, cnt16);
    bucket_scan<<<1, 64, 0, stream>>>(cnt16, bptr16, cur16);
    bucket_scatter<<<N_EDGES / 256, 256, 0, stream>>>(src, dst, ety, cur16, bedge, cnt);

    scan1<<<NCHUNK, 256, 0, stream>>>(cnt, part);
    scan2<<<1, 64, 0, stream>>>(part, pbase);
    scan3<<<NCHUNK, 256, 0, stream>>>(cnt, pbase, rowp);

    fused_att<<<dim3(128, N_REL), 256, 0, stream>>>(entb, W_R, rel, bedge, bptr16, rowp, pair);

    fused_layer1<<<N_ENT / 4, 256, 0, stream>>>(ent, entb, W0, rowp, pair, h1b, out);
    fused_layer2<<<N_ENT / 4, 256, 0, stream>>>(h1b, W1, rowp, pair, out);
}